// Round 1
// baseline (1468.700 us; speedup 1.0000x reference)
//
#include <hip/hip_runtime.h>
#include <cstdint>
#include <cstddef>

// Problem constants (verified against in_sizes at runtime where cheap)
#define F_IN 128
#define HC12 256   // HEADS*HID for layers 1/2
#define HC3 484    // OUT_HEADS*N_CLS for layer 3
#define NCLS 121

static __device__ __forceinline__ float lrelu(float x) { return x > 0.f ? x : 0.2f * x; }

// ---------------- CSR build ----------------
__global__ void hist_kernel(const int* __restrict__ dst, int* __restrict__ deg, int E) {
    int e = blockIdx.x * 256 + threadIdx.x;
    if (e < E) atomicAdd(&deg[dst[e]], 1);
}

__global__ __launch_bounds__(1024) void scan_kernel(const int* __restrict__ deg,
                                                    int* __restrict__ rowp, int N) {
    __shared__ int buf[1024];
    __shared__ int s_carry;
    int tid = threadIdx.x;
    if (tid == 0) { rowp[0] = 0; s_carry = 0; }
    __syncthreads();
    for (int base = 0; base < N; base += 1024) {
        int i = base + tid;
        int v = (i < N) ? deg[i] : 0;
        buf[tid] = v;
        __syncthreads();
        // Hillis-Steele inclusive scan
        for (int off = 1; off < 1024; off <<= 1) {
            int t = (tid >= off) ? buf[tid - off] : 0;
            __syncthreads();
            buf[tid] += t;
            __syncthreads();
        }
        int carry = s_carry;
        if (i < N) rowp[i + 1] = carry + buf[tid];
        __syncthreads();
        if (tid == 1023) s_carry = carry + buf[1023];
        __syncthreads();
    }
}

__global__ void scatter_kernel(const int* __restrict__ src, const int* __restrict__ dst,
                               const int* __restrict__ rowp, int* __restrict__ cur,
                               int* __restrict__ col, int E) {
    int e = blockIdx.x * 256 + threadIdx.x;
    if (e < E) {
        int d = dst[e];
        int pos = rowp[d] + atomicAdd(&cur[d], 1);
        col[pos] = src[e];
    }
}

// ---------------- fp32 tiled GEMM: C[M,N] = A[M,K] @ B[K,N] (+bias) ----------------
// block (16,16), 64x64 tile, K-tile 16, 4x4 per thread. K must be divisible by 16.
__global__ __launch_bounds__(256) void gemm_bias(const float* __restrict__ A,
                                                 const float* __restrict__ B,
                                                 const float* __restrict__ bias,
                                                 float* __restrict__ C,
                                                 int M, int N, int K) {
    __shared__ float As[16][65];
    __shared__ float Bs[16][65];
    int tx = threadIdx.x, ty = threadIdx.y;
    int t = ty * 16 + tx;
    int n0 = blockIdx.x * 64, m0 = blockIdx.y * 64;
    float acc[4][4] = {};
    for (int kt = 0; kt < K; kt += 16) {
#pragma unroll
        for (int i = 0; i < 4; i++) {
            int lin = t + i * 256;
            int kk = lin & 15, mi = lin >> 4;
            int r = m0 + mi;
            As[kk][mi] = (r < M) ? A[(size_t)r * K + kt + kk] : 0.f;
        }
#pragma unroll
        for (int i = 0; i < 4; i++) {
            int lin = t + i * 256;
            int ni = lin & 63, kk = lin >> 6;
            int c = n0 + ni;
            Bs[kk][ni] = (c < N) ? B[(size_t)(kt + kk) * N + c] : 0.f;
        }
        __syncthreads();
#pragma unroll
        for (int kk = 0; kk < 16; kk++) {
            float a[4], b[4];
#pragma unroll
            for (int i = 0; i < 4; i++) a[i] = As[kk][ty * 4 + i];
#pragma unroll
            for (int j = 0; j < 4; j++) b[j] = Bs[kk][tx * 4 + j];
#pragma unroll
            for (int i = 0; i < 4; i++)
#pragma unroll
                for (int j = 0; j < 4; j++) acc[i][j] += a[i] * b[j];
        }
        __syncthreads();
    }
#pragma unroll
    for (int i = 0; i < 4; i++) {
        int r = m0 + ty * 4 + i;
        if (r >= M) continue;
#pragma unroll
        for (int j = 0; j < 4; j++) {
            int c = n0 + tx * 4 + j;
            if (c >= N) continue;
            float v = acc[i][j];
            if (bias) v += bias[c];
            C[(size_t)r * N + c] = v;
        }
    }
}

// ---------------- per-node attention coefficients ----------------
// grid = N blocks, 256 threads: wave w handles head w (H==4)
__global__ __launch_bounds__(256) void alpha_kernel(const float* __restrict__ xh,
                                                    const float* __restrict__ a_s,
                                                    const float* __restrict__ a_d,
                                                    float* __restrict__ as_o,
                                                    float* __restrict__ ad_o, int C) {
    int n = blockIdx.x;
    int w = threadIdx.x >> 6, lane = threadIdx.x & 63;
    const float* row = xh + (size_t)n * 4 * C + (size_t)w * C;
    float ss = 0.f, sd = 0.f;
    for (int c = lane; c < C; c += 64) {
        float v = row[c];
        ss += v * a_s[w * C + c];
        sd += v * a_d[w * C + c];
    }
    for (int o = 32; o; o >>= 1) {
        ss += __shfl_xor(ss, o, 64);
        sd += __shfl_xor(sd, o, 64);
    }
    if (!lane) {
        as_o[n * 4 + w] = ss;
        ad_o[n * 4 + w] = sd;
    }
}

// ---------------- edge-softmax + aggregate, HC=256 (layers 1/2) ----------------
// out[n,hc] = elu( sum_e alpha * xh[src,hc] + bias[hc] + res[n,hc] )
__global__ __launch_bounds__(256) void agg_kernel_256(const float* __restrict__ xh,
                                                      const int* __restrict__ rowp,
                                                      const int* __restrict__ col,
                                                      const float* __restrict__ asrc,
                                                      const float* __restrict__ adst,
                                                      const float* __restrict__ bias,
                                                      const float* __restrict__ res,
                                                      float* __restrict__ out) {
    int n = blockIdx.x, tid = threadIdx.x;
    int r0 = rowp[n], deg = rowp[n + 1] - r0;
    __shared__ float sm[4], srd[4];
    __shared__ int s_src[64];
    __shared__ float s_alpha[64][4];
    int w = tid >> 6, lane = tid & 63;
    float adn = adst[n * 4 + w];
    // phase A: per-head max then sum(exp)
    float m = -3.4e38f;
    for (int k = lane; k < deg; k += 64) {
        int s = col[r0 + k];
        m = fmaxf(m, lrelu(asrc[s * 4 + w] + adn));
    }
    for (int o = 32; o; o >>= 1) m = fmaxf(m, __shfl_xor(m, o, 64));
    float sum = 0.f;
    for (int k = lane; k < deg; k += 64) {
        int s = col[r0 + k];
        sum += expf(lrelu(asrc[s * 4 + w] + adn) - m);
    }
    for (int o = 32; o; o >>= 1) sum += __shfl_xor(sum, o, 64);
    if (!lane) { sm[w] = m; srd[w] = 1.f / (sum + 1e-16f); }
    __syncthreads();
    // phase B: chunked accumulate (thread tid owns channel tid; head = tid>>6)
    float acc = 0.f;
    int h = tid >> 6;
    for (int kb = 0; kb < deg; kb += 64) {
        int cn = min(64, deg - kb);
        __syncthreads();
        for (int idx = tid; idx < cn * 4; idx += 256) {
            int kk = idx >> 2, hh = idx & 3;
            int s = col[r0 + kb + kk];
            if (hh == 0) s_src[kk] = s;
            float l = lrelu(asrc[s * 4 + hh] + adst[n * 4 + hh]);
            s_alpha[kk][hh] = expf(l - sm[hh]) * srd[hh];
        }
        __syncthreads();
        for (int kk = 0; kk < cn; kk++) {
            acc += s_alpha[kk][h] * xh[(size_t)s_src[kk] * HC12 + tid];
        }
    }
    float v = acc + bias[tid] + res[(size_t)n * HC12 + tid];
    out[(size_t)n * HC12 + tid] = v > 0.f ? v : expm1f(v);
}

// ---------------- layer 3: HC=484, mean over 4 heads + b3 + lin3 -> d_out ----------------
__global__ __launch_bounds__(256) void agg_out_kernel(const float* __restrict__ xh,
                                                      const int* __restrict__ rowp,
                                                      const int* __restrict__ col,
                                                      const float* __restrict__ asrc,
                                                      const float* __restrict__ adst,
                                                      const float* __restrict__ b3,
                                                      const float* __restrict__ lin3,
                                                      float* __restrict__ out) {
    int n = blockIdx.x, tid = threadIdx.x;
    int r0 = rowp[n], deg = rowp[n + 1] - r0;
    __shared__ float sm[4], srd[4];
    __shared__ int s_src[64];
    __shared__ float s_alpha[64][4];
    __shared__ float sagg[HC3];
    int w = tid >> 6, lane = tid & 63;
    float adn = adst[n * 4 + w];
    float m = -3.4e38f;
    for (int k = lane; k < deg; k += 64) {
        int s = col[r0 + k];
        m = fmaxf(m, lrelu(asrc[s * 4 + w] + adn));
    }
    for (int o = 32; o; o >>= 1) m = fmaxf(m, __shfl_xor(m, o, 64));
    float sum = 0.f;
    for (int k = lane; k < deg; k += 64) {
        int s = col[r0 + k];
        sum += expf(lrelu(asrc[s * 4 + w] + adn) - m);
    }
    for (int o = 32; o; o >>= 1) sum += __shfl_xor(sum, o, 64);
    if (!lane) { sm[w] = m; srd[w] = 1.f / (sum + 1e-16f); }
    __syncthreads();
    int ch1 = tid + 256;
    bool has1 = ch1 < HC3;
    int h0 = tid >= 363 ? 3 : (tid >= 242 ? 2 : (tid >= 121 ? 1 : 0));
    int h1v = ch1 >= 363 ? 3 : 2;
    float acc0 = 0.f, acc1 = 0.f;
    for (int kb = 0; kb < deg; kb += 64) {
        int cn = min(64, deg - kb);
        __syncthreads();
        for (int idx = tid; idx < cn * 4; idx += 256) {
            int kk = idx >> 2, hh = idx & 3;
            int s = col[r0 + kb + kk];
            if (hh == 0) s_src[kk] = s;
            float l = lrelu(asrc[s * 4 + hh] + adst[n * 4 + hh]);
            s_alpha[kk][hh] = expf(l - sm[hh]) * srd[hh];
        }
        __syncthreads();
        for (int kk = 0; kk < cn; kk++) {
            const float* row = xh + (size_t)s_src[kk] * HC3;
            acc0 += s_alpha[kk][h0] * row[tid];
            if (has1) acc1 += s_alpha[kk][h1v] * row[ch1];
        }
    }
    sagg[tid] = acc0;
    if (has1) sagg[ch1] = acc1;
    __syncthreads();
    if (tid < NCLS) {
        float o = 0.25f * (sagg[tid] + sagg[NCLS + tid] + sagg[2 * NCLS + tid] + sagg[3 * NCLS + tid])
                  + b3[tid] + lin3[(size_t)n * NCLS + tid];
        out[(size_t)n * NCLS + tid] = o;
    }
}

extern "C" void kernel_launch(void* const* d_in, const int* in_sizes, int n_in,
                              void* d_out, int out_size, void* d_ws, size_t ws_size,
                              hipStream_t stream) {
    const float* x   = (const float*)d_in[0];
    const int*   ei  = (const int*)d_in[1];
    const float* W1  = (const float*)d_in[2];
    const float* a1s = (const float*)d_in[3];
    const float* a1d = (const float*)d_in[4];
    const float* b1  = (const float*)d_in[5];
    const float* l1W = (const float*)d_in[6];
    const float* l1b = (const float*)d_in[7];
    const float* W2  = (const float*)d_in[8];
    const float* a2s = (const float*)d_in[9];
    const float* a2d = (const float*)d_in[10];
    const float* b2  = (const float*)d_in[11];
    const float* W3  = (const float*)d_in[12];
    const float* a3s = (const float*)d_in[13];
    const float* a3d = (const float*)d_in[14];
    const float* b3  = (const float*)d_in[15];
    const float* l3W = (const float*)d_in[16];
    const float* l3b = (const float*)d_in[17];

    const int N = in_sizes[0] / F_IN;   // 50000
    const int E = in_sizes[1] / 2;      // 400000
    const int* srcv = ei;
    const int* dstv = ei + E;

    char* ws = (char*)d_ws;
    size_t off = 0;
    auto alloc = [&](size_t bytes) -> char* {
        char* p = ws + off;
        off += (bytes + 255) & ~(size_t)255;
        return p;
    };
    float* xh   = (float*)alloc((size_t)N * HC3 * 4);
    float* h1   = (float*)alloc((size_t)N * HC12 * 4);
    float* h2   = (float*)alloc((size_t)N * HC12 * 4);
    float* lin  = (float*)alloc((size_t)N * HC12 * 4);
    float* as_  = (float*)alloc((size_t)N * 4 * 4);
    float* ad_  = (float*)alloc((size_t)N * 4 * 4);
    int* rowp   = (int*)alloc((size_t)(N + 1) * 4);
    int* degc   = (int*)alloc((size_t)N * 4);
    int* cur    = (int*)alloc((size_t)N * 4);
    int* col    = (int*)alloc((size_t)E * 4);
    (void)ws_size; (void)n_in; (void)out_size;

    // ---- CSR build (recomputed every call; ws is re-poisoned) ----
    hipMemsetAsync(degc, 0, (size_t)N * 4, stream);
    hipMemsetAsync(cur, 0, (size_t)N * 4, stream);
    hist_kernel<<<(E + 255) / 256, 256, 0, stream>>>(dstv, degc, E);
    scan_kernel<<<1, 1024, 0, stream>>>(degc, rowp, N);
    scatter_kernel<<<(E + 255) / 256, 256, 0, stream>>>(srcv, dstv, rowp, cur, col, E);

    dim3 blk(16, 16);
    int mgrid = (N + 63) / 64;

    // ---- layer 1 ----
    gemm_bias<<<dim3(4, mgrid), blk, 0, stream>>>(x, W1, nullptr, xh, N, HC12, F_IN);
    gemm_bias<<<dim3(4, mgrid), blk, 0, stream>>>(x, l1W, l1b, lin, N, HC12, F_IN);
    alpha_kernel<<<N, 256, 0, stream>>>(xh, a1s, a1d, as_, ad_, 64);
    agg_kernel_256<<<N, 256, 0, stream>>>(xh, rowp, col, as_, ad_, b1, lin, h1);

    // ---- layer 2 ----
    gemm_bias<<<dim3(4, mgrid), blk, 0, stream>>>(h1, W2, nullptr, xh, N, HC12, HC12);
    alpha_kernel<<<N, 256, 0, stream>>>(xh, a2s, a2d, as_, ad_, 64);
    agg_kernel_256<<<N, 256, 0, stream>>>(xh, rowp, col, as_, ad_, b2, h1, h2);

    // ---- layer 3 ----
    gemm_bias<<<dim3(8, mgrid), blk, 0, stream>>>(h2, W3, nullptr, xh, N, HC3, HC12);
    gemm_bias<<<dim3(2, mgrid), blk, 0, stream>>>(h2, l3W, l3b, lin, N, NCLS, HC12);
    alpha_kernel<<<N, 256, 0, stream>>>(xh, a3s, a3d, as_, ad_, NCLS);
    agg_out_kernel<<<N, 256, 0, stream>>>(xh, rowp, col, as_, ad_, b3, lin, (float*)d_out);
}

// Round 3
// 1009.832 us; speedup vs baseline: 1.4544x; 1.4544x over previous
//
#include <hip/hip_runtime.h>
#include <cstdint>
#include <cstddef>

#define F_IN 128
#define HC12 256   // HEADS*HID for layers 1/2
#define HC3 484    // OUT_HEADS*N_CLS for layer 3
#define NCLS 121

typedef unsigned short u16;
typedef __attribute__((ext_vector_type(8))) short short8;
typedef __attribute__((ext_vector_type(4))) float float4v;

static __device__ __forceinline__ float lrelu(float x) { return x > 0.f ? x : 0.2f * x; }

static __device__ __forceinline__ u16 f2bf(float f) {
    union { float f; unsigned u; } v; v.f = f;
    unsigned r = v.u + 0x7FFF + ((v.u >> 16) & 1);
    return (u16)(r >> 16);
}
static __device__ __forceinline__ float bf2f(u16 h) {
    union { unsigned u; float f; } v; v.u = ((unsigned)h) << 16;
    return v.f;
}

// ---------------- CSR build ----------------
__global__ void hist_kernel(const int* __restrict__ dst, int* __restrict__ deg, int E) {
    int e = blockIdx.x * 256 + threadIdx.x;
    if (e < E) atomicAdd(&deg[dst[e]], 1);
}

__global__ __launch_bounds__(1024) void scan_kernel(const int* __restrict__ deg,
                                                    int* __restrict__ rowp, int N) {
    __shared__ int buf[1024];
    __shared__ int s_carry;
    int tid = threadIdx.x;
    if (tid == 0) { rowp[0] = 0; s_carry = 0; }
    __syncthreads();
    for (int base = 0; base < N; base += 1024) {
        int i = base + tid;
        int v = (i < N) ? deg[i] : 0;
        buf[tid] = v;
        __syncthreads();
        for (int off = 1; off < 1024; off <<= 1) {
            int t = (tid >= off) ? buf[tid - off] : 0;
            __syncthreads();
            buf[tid] += t;
            __syncthreads();
        }
        int carry = s_carry;
        if (i < N) rowp[i + 1] = carry + buf[tid];
        __syncthreads();
        if (tid == 1023) s_carry = carry + buf[1023];
        __syncthreads();
    }
}

__global__ void scatter_kernel(const int* __restrict__ src, const int* __restrict__ dst,
                               const int* __restrict__ rowp, int* __restrict__ cur,
                               int* __restrict__ col, int E) {
    int e = blockIdx.x * 256 + threadIdx.x;
    if (e < E) {
        int d = dst[e];
        int pos = rowp[d] + atomicAdd(&cur[d], 1);
        col[pos] = src[e];
    }
}

// fp32 B[K][N] -> bf16 BT_hi/lo [N][K]  (weights only; tiny buffers)
__global__ void splitT_kernel(const float* __restrict__ B, u16* __restrict__ hiT,
                              u16* __restrict__ loT, int K, int N) {
    int n = blockIdx.x * 16 + threadIdx.x;
    int k = blockIdx.y * 16 + threadIdx.y;
    if (n < N && k < K) {
        float v = B[(size_t)k * N + n];
        u16 h = f2bf(v);
        float r = v - bf2f(h);
        hiT[(size_t)n * K + k] = h;
        loT[(size_t)n * K + k] = f2bf(r);
    }
}

// ---------------- split-bf16 MFMA GEMM: C[M,N] = A[M,K] @ B[K,N] (+bias) ----------------
// A: fp32 row-major [M][K], split hi/lo in-register during staging.
// B: bf16 hi/lo TRANSPOSED [N][K] (pre-split weights).
// Block: 256 thr (4 waves), tile 128(M) x 64(N), K-chunk 32.
#define BM 128
#define BN 64
#define BK 32
#define LDA 40   // padded LDS row stride (bf16 elems); 80 B = 16B-aligned

__global__ __launch_bounds__(256) void gemm_mfma_split(const float* __restrict__ A,
                                                       const u16* __restrict__ BThi,
                                                       const u16* __restrict__ BTlo,
                                                       const float* __restrict__ bias,
                                                       float* __restrict__ C,
                                                       int M, int N, int K) {
    __shared__ __align__(16) u16 sAh[BM * LDA];
    __shared__ __align__(16) u16 sAl[BM * LDA];
    __shared__ __align__(16) u16 sBh[BN * LDA];
    __shared__ __align__(16) u16 sBl[BN * LDA];
    int tid = threadIdx.x;
    int wave = tid >> 6, lane = tid & 63;
    int m0 = blockIdx.y * BM, n0 = blockIdx.x * BN;
    int fm = lane & 15;   // row-in-frag (A) / col-in-frag (B, C)
    int q = lane >> 4;    // quad

    float4v acc[2][4];
#pragma unroll
    for (int i = 0; i < 2; i++)
#pragma unroll
        for (int j = 0; j < 4; j++) acc[i][j] = (float4v){0.f, 0.f, 0.f, 0.f};

    const uint4 zero4 = {0u, 0u, 0u, 0u};

    for (int kc = 0; kc < K; kc += BK) {
        // stage A: 128x32 fp32 -> hi/lo bf16. 8 elems (2 float4) per thread per pass.
#pragma unroll
        for (int j = 0; j < 2; j++) {
            int e = (tid + j * 256) * 8;
            int row = e >> 5, colk = e & 31;
            int gr = m0 + row;
            float va[8];
            if (gr < M) {
                float4 f0 = *(const float4*)&A[(size_t)gr * K + kc + colk];
                float4 f1 = *(const float4*)&A[(size_t)gr * K + kc + colk + 4];
                va[0] = f0.x; va[1] = f0.y; va[2] = f0.z; va[3] = f0.w;
                va[4] = f1.x; va[5] = f1.y; va[6] = f1.z; va[7] = f1.w;
            } else {
#pragma unroll
                for (int i = 0; i < 8; i++) va[i] = 0.f;
            }
            short8 vh, vl;
#pragma unroll
            for (int i = 0; i < 8; i++) {
                u16 h = f2bf(va[i]);
                vh[i] = (short)h;
                vl[i] = (short)f2bf(va[i] - bf2f(h));
            }
            *(short8*)&sAh[row * LDA + colk] = vh;
            *(short8*)&sAl[row * LDA + colk] = vl;
        }
        // stage B^T: 64x32 bf16 hi/lo, 1 uint4 per thread per version
        {
            int e = tid * 8;
            int nn = e >> 5, colk = e & 31;
            int gn = n0 + nn;
            uint4 vh = zero4, vl = zero4;
            if (gn < N) {
                vh = *(const uint4*)&BThi[(size_t)gn * K + kc + colk];
                vl = *(const uint4*)&BTlo[(size_t)gn * K + kc + colk];
            }
            *(uint4*)&sBh[nn * LDA + colk] = vh;
            *(uint4*)&sBl[nn * LDA + colk] = vl;
        }
        __syncthreads();

        short8 bh[4], bl[4];
#pragma unroll
        for (int ni = 0; ni < 4; ni++) {
            int nn = ni * 16 + fm;
            bh[ni] = *(const short8*)&sBh[nn * LDA + q * 8];
            bl[ni] = *(const short8*)&sBl[nn * LDA + q * 8];
        }
#pragma unroll
        for (int mi = 0; mi < 2; mi++) {
            int row = wave * 32 + mi * 16 + fm;
            short8 ah = *(const short8*)&sAh[row * LDA + q * 8];
            short8 al = *(const short8*)&sAl[row * LDA + q * 8];
#pragma unroll
            for (int ni = 0; ni < 4; ni++) {
                acc[mi][ni] = __builtin_amdgcn_mfma_f32_16x16x32_bf16(ah, bh[ni], acc[mi][ni], 0, 0, 0);
                acc[mi][ni] = __builtin_amdgcn_mfma_f32_16x16x32_bf16(ah, bl[ni], acc[mi][ni], 0, 0, 0);
                acc[mi][ni] = __builtin_amdgcn_mfma_f32_16x16x32_bf16(al, bh[ni], acc[mi][ni], 0, 0, 0);
            }
        }
        __syncthreads();
    }

    // epilogue: C[row=(q*4+r), col=fm] within each 16x16 frag
#pragma unroll
    for (int mi = 0; mi < 2; mi++) {
#pragma unroll
        for (int ni = 0; ni < 4; ni++) {
            int colg = n0 + ni * 16 + fm;
            if (colg >= N) continue;
            float bv = bias ? bias[colg] : 0.f;
#pragma unroll
            for (int r = 0; r < 4; r++) {
                int rowg = m0 + wave * 32 + mi * 16 + q * 4 + r;
                if (rowg < M) C[(size_t)rowg * N + colg] = acc[mi][ni][r] + bv;
            }
        }
    }
}

// ---------------- per-node attention coefficients ----------------
__global__ __launch_bounds__(256) void alpha_kernel(const float* __restrict__ xh,
                                                    const float* __restrict__ a_s,
                                                    const float* __restrict__ a_d,
                                                    float* __restrict__ as_o,
                                                    float* __restrict__ ad_o, int C) {
    int n = blockIdx.x;
    int w = threadIdx.x >> 6, lane = threadIdx.x & 63;
    const float* row = xh + (size_t)n * 4 * C + (size_t)w * C;
    float ss = 0.f, sd = 0.f;
    for (int c = lane; c < C; c += 64) {
        float v = row[c];
        ss += v * a_s[w * C + c];
        sd += v * a_d[w * C + c];
    }
    for (int o = 32; o; o >>= 1) {
        ss += __shfl_xor(ss, o, 64);
        sd += __shfl_xor(sd, o, 64);
    }
    if (!lane) {
        as_o[n * 4 + w] = ss;
        ad_o[n * 4 + w] = sd;
    }
}

// ---------------- edge-softmax + aggregate, HC=256 (layers 1/2) ----------------
// NOTE: res and out may alias (in-place residual) — no __restrict__ on them.
__global__ __launch_bounds__(256) void agg_kernel_256(const float* __restrict__ xh,
                                                      const int* __restrict__ rowp,
                                                      const int* __restrict__ col,
                                                      const float* __restrict__ asrc,
                                                      const float* __restrict__ adst,
                                                      const float* __restrict__ bias,
                                                      const float* res,
                                                      float* out) {
    int n = blockIdx.x, tid = threadIdx.x;
    int r0 = rowp[n], deg = rowp[n + 1] - r0;
    __shared__ float sm[4], srd[4];
    __shared__ int s_src[64];
    __shared__ float s_alpha[64][4];
    int w = tid >> 6, lane = tid & 63;
    float adn = adst[n * 4 + w];
    float m = -3.4e38f;
    for (int k = lane; k < deg; k += 64) {
        int s = col[r0 + k];
        m = fmaxf(m, lrelu(asrc[s * 4 + w] + adn));
    }
    for (int o = 32; o; o >>= 1) m = fmaxf(m, __shfl_xor(m, o, 64));
    float sum = 0.f;
    for (int k = lane; k < deg; k += 64) {
        int s = col[r0 + k];
        sum += expf(lrelu(asrc[s * 4 + w] + adn) - m);
    }
    for (int o = 32; o; o >>= 1) sum += __shfl_xor(sum, o, 64);
    if (!lane) { sm[w] = m; srd[w] = 1.f / (sum + 1e-16f); }
    __syncthreads();
    float acc = 0.f;
    int h = tid >> 6;
    for (int kb = 0; kb < deg; kb += 64) {
        int cn = min(64, deg - kb);
        __syncthreads();
        for (int idx = tid; idx < cn * 4; idx += 256) {
            int kk = idx >> 2, hh = idx & 3;
            int s = col[r0 + kb + kk];
            if (hh == 0) s_src[kk] = s;
            float l = lrelu(asrc[s * 4 + hh] + adst[n * 4 + hh]);
            s_alpha[kk][hh] = expf(l - sm[hh]) * srd[hh];
        }
        __syncthreads();
        for (int kk = 0; kk < cn; kk++) {
            acc += s_alpha[kk][h] * xh[(size_t)s_src[kk] * HC12 + tid];
        }
    }
    float v = acc + bias[tid] + res[(size_t)n * HC12 + tid];
    out[(size_t)n * HC12 + tid] = v > 0.f ? v : expm1f(v);
}

// ---------------- layer 3: HC=484, mean over 4 heads + b3 + lin3 -> d_out ----------------
__global__ __launch_bounds__(256) void agg_out_kernel(const float* __restrict__ xh,
                                                      const int* __restrict__ rowp,
                                                      const int* __restrict__ col,
                                                      const float* __restrict__ asrc,
                                                      const float* __restrict__ adst,
                                                      const float* __restrict__ b3,
                                                      const float* __restrict__ lin3,
                                                      float* __restrict__ out) {
    int n = blockIdx.x, tid = threadIdx.x;
    int r0 = rowp[n], deg = rowp[n + 1] - r0;
    __shared__ float sm[4], srd[4];
    __shared__ int s_src[64];
    __shared__ float s_alpha[64][4];
    __shared__ float sagg[HC3];
    int w = tid >> 6, lane = tid & 63;
    float adn = adst[n * 4 + w];
    float m = -3.4e38f;
    for (int k = lane; k < deg; k += 64) {
        int s = col[r0 + k];
        m = fmaxf(m, lrelu(asrc[s * 4 + w] + adn));
    }
    for (int o = 32; o; o >>= 1) m = fmaxf(m, __shfl_xor(m, o, 64));
    float sum = 0.f;
    for (int k = lane; k < deg; k += 64) {
        int s = col[r0 + k];
        sum += expf(lrelu(asrc[s * 4 + w] + adn) - m);
    }
    for (int o = 32; o; o >>= 1) sum += __shfl_xor(sum, o, 64);
    if (!lane) { sm[w] = m; srd[w] = 1.f / (sum + 1e-16f); }
    __syncthreads();
    int ch1 = tid + 256;
    bool has1 = ch1 < HC3;
    int h0 = tid >= 363 ? 3 : (tid >= 242 ? 2 : (tid >= 121 ? 1 : 0));
    int h1v = ch1 >= 363 ? 3 : 2;
    float acc0 = 0.f, acc1 = 0.f;
    for (int kb = 0; kb < deg; kb += 64) {
        int cn = min(64, deg - kb);
        __syncthreads();
        for (int idx = tid; idx < cn * 4; idx += 256) {
            int kk = idx >> 2, hh = idx & 3;
            int s = col[r0 + kb + kk];
            if (hh == 0) s_src[kk] = s;
            float l = lrelu(asrc[s * 4 + hh] + adst[n * 4 + hh]);
            s_alpha[kk][hh] = expf(l - sm[hh]) * srd[hh];
        }
        __syncthreads();
        for (int kk = 0; kk < cn; kk++) {
            const float* row = xh + (size_t)s_src[kk] * HC3;
            acc0 += s_alpha[kk][h0] * row[tid];
            if (has1) acc1 += s_alpha[kk][h1v] * row[ch1];
        }
    }
    sagg[tid] = acc0;
    if (has1) sagg[ch1] = acc1;
    __syncthreads();
    if (tid < NCLS) {
        float o = 0.25f * (sagg[tid] + sagg[NCLS + tid] + sagg[2 * NCLS + tid] + sagg[3 * NCLS + tid])
                  + b3[tid] + lin3[(size_t)n * NCLS + tid];
        out[(size_t)n * NCLS + tid] = o;
    }
}

extern "C" void kernel_launch(void* const* d_in, const int* in_sizes, int n_in,
                              void* d_out, int out_size, void* d_ws, size_t ws_size,
                              hipStream_t stream) {
    const float* x   = (const float*)d_in[0];
    const int*   ei  = (const int*)d_in[1];
    const float* W1  = (const float*)d_in[2];
    const float* a1s = (const float*)d_in[3];
    const float* a1d = (const float*)d_in[4];
    const float* b1  = (const float*)d_in[5];
    const float* l1W = (const float*)d_in[6];
    const float* l1b = (const float*)d_in[7];
    const float* W2  = (const float*)d_in[8];
    const float* a2s = (const float*)d_in[9];
    const float* a2d = (const float*)d_in[10];
    const float* b2  = (const float*)d_in[11];
    const float* W3  = (const float*)d_in[12];
    const float* a3s = (const float*)d_in[13];
    const float* a3d = (const float*)d_in[14];
    const float* b3  = (const float*)d_in[15];
    const float* l3W = (const float*)d_in[16];
    const float* l3b = (const float*)d_in[17];

    const int N = in_sizes[0] / F_IN;   // 50000
    const int E = in_sizes[1] / 2;      // 400000
    const int* srcv = ei;
    const int* dstv = ei + E;

    char* ws = (char*)d_ws;
    size_t off = 0;
    auto alloc = [&](size_t bytes) -> char* {
        char* p = ws + off;
        off += (bytes + 255) & ~(size_t)255;
        return p;
    };
    // ~228 MB total (R1's 254 MB fit; R2's 332 MB crashed -> stay lean)
    float* xh   = (float*)alloc((size_t)N * HC3 * 4);
    float* h1   = (float*)alloc((size_t)N * HC12 * 4);
    float* h2   = (float*)alloc((size_t)N * HC12 * 4);
    float* lin  = (float*)alloc((size_t)N * NCLS * 4);
    float* as_  = (float*)alloc((size_t)N * 4 * 4);
    float* ad_  = (float*)alloc((size_t)N * 4 * 4);
    int* rowp   = (int*)alloc((size_t)(N + 1) * 4);
    int* degc   = (int*)alloc((size_t)N * 4);
    int* cur    = (int*)alloc((size_t)N * 4);
    int* col    = (int*)alloc((size_t)E * 4);
    u16* W1T_h  = (u16*)alloc((size_t)HC12 * F_IN * 2);
    u16* W1T_l  = (u16*)alloc((size_t)HC12 * F_IN * 2);
    u16* L1T_h  = (u16*)alloc((size_t)HC12 * F_IN * 2);
    u16* L1T_l  = (u16*)alloc((size_t)HC12 * F_IN * 2);
    u16* W2T_h  = (u16*)alloc((size_t)HC12 * HC12 * 2);
    u16* W2T_l  = (u16*)alloc((size_t)HC12 * HC12 * 2);
    u16* W3T_h  = (u16*)alloc((size_t)HC3 * HC12 * 2);
    u16* W3T_l  = (u16*)alloc((size_t)HC3 * HC12 * 2);
    u16* L3T_h  = (u16*)alloc((size_t)NCLS * HC12 * 2);
    u16* L3T_l  = (u16*)alloc((size_t)NCLS * HC12 * 2);
    (void)ws_size; (void)n_in; (void)out_size;

    // ---- CSR build ----
    hipMemsetAsync(degc, 0, (size_t)N * 4, stream);
    hipMemsetAsync(cur, 0, (size_t)N * 4, stream);
    hist_kernel<<<(E + 255) / 256, 256, 0, stream>>>(dstv, degc, E);
    scan_kernel<<<1, 1024, 0, stream>>>(degc, rowp, N);
    scatter_kernel<<<(E + 255) / 256, 256, 0, stream>>>(srcv, dstv, rowp, cur, col, E);

    // ---- weight splits (transposed) ----
    dim3 tb(16, 16);
    splitT_kernel<<<dim3((HC12 + 15) / 16, (F_IN + 15) / 16), tb, 0, stream>>>(W1, W1T_h, W1T_l, F_IN, HC12);
    splitT_kernel<<<dim3((HC12 + 15) / 16, (F_IN + 15) / 16), tb, 0, stream>>>(l1W, L1T_h, L1T_l, F_IN, HC12);
    splitT_kernel<<<dim3((HC12 + 15) / 16, (HC12 + 15) / 16), tb, 0, stream>>>(W2, W2T_h, W2T_l, HC12, HC12);
    splitT_kernel<<<dim3((HC3 + 15) / 16, (HC12 + 15) / 16), tb, 0, stream>>>(W3, W3T_h, W3T_l, HC12, HC3);
    splitT_kernel<<<dim3((NCLS + 15) / 16, (HC12 + 15) / 16), tb, 0, stream>>>(l3W, L3T_h, L3T_l, HC12, NCLS);

    int mgrid = (N + BM - 1) / BM;

    // ---- layer 1 ----
    gemm_mfma_split<<<dim3(4, mgrid), 256, 0, stream>>>(x, W1T_h, W1T_l, nullptr, xh, N, HC12, F_IN);
    gemm_mfma_split<<<dim3(4, mgrid), 256, 0, stream>>>(x, L1T_h, L1T_l, l1b, h1, N, HC12, F_IN);
    alpha_kernel<<<N, 256, 0, stream>>>(xh, a1s, a1d, as_, ad_, 64);
    agg_kernel_256<<<N, 256, 0, stream>>>(xh, rowp, col, as_, ad_, b1, h1, h1);  // in-place residual

    // ---- layer 2 ----
    gemm_mfma_split<<<dim3(4, mgrid), 256, 0, stream>>>(h1, W2T_h, W2T_l, nullptr, xh, N, HC12, HC12);
    alpha_kernel<<<N, 256, 0, stream>>>(xh, a2s, a2d, as_, ad_, 64);
    agg_kernel_256<<<N, 256, 0, stream>>>(xh, rowp, col, as_, ad_, b2, h1, h2);

    // ---- layer 3 ----
    gemm_mfma_split<<<dim3(8, mgrid), 256, 0, stream>>>(h2, W3T_h, W3T_l, nullptr, xh, N, HC3, HC12);
    gemm_mfma_split<<<dim3(2, mgrid), 256, 0, stream>>>(h2, L3T_h, L3T_l, l3b, lin, N, NCLS, HC12);
    alpha_kernel<<<N, 256, 0, stream>>>(xh, a3s, a3d, as_, ad_, NCLS);
    agg_out_kernel<<<N, 256, 0, stream>>>(xh, rowp, col, as_, ad_, b3, lin, (float*)d_out);
}

// Round 4
// 946.361 us; speedup vs baseline: 1.5519x; 1.0671x over previous
//
#include <hip/hip_runtime.h>
#include <cstdint>
#include <cstddef>

#define F_IN 128
#define HC12 256   // HEADS*HID for layers 1/2
#define HC3 484    // OUT_HEADS*N_CLS for layer 3
#define NCLS 121

typedef unsigned short u16;
typedef __attribute__((ext_vector_type(8))) short short8;
typedef __attribute__((ext_vector_type(4))) float float4v;

static __device__ __forceinline__ float lrelu(float x) { return x > 0.f ? x : 0.2f * x; }

static __device__ __forceinline__ u16 f2bf(float f) {
    union { float f; unsigned u; } v; v.f = f;
    unsigned r = v.u + 0x7FFF + ((v.u >> 16) & 1);
    return (u16)(r >> 16);
}
static __device__ __forceinline__ float bf2f(u16 h) {
    union { unsigned u; float f; } v; v.u = ((unsigned)h) << 16;
    return v.f;
}

// ---------------- CSR build ----------------
__global__ void hist_kernel(const int* __restrict__ dst, int* __restrict__ deg, int E) {
    int e = blockIdx.x * 256 + threadIdx.x;
    if (e < E) atomicAdd(&deg[dst[e]], 1);
}

// shfl-based scan: 2 barriers per 1024-chunk instead of 20
__global__ __launch_bounds__(1024) void scan_kernel(const int* __restrict__ deg,
                                                    int* __restrict__ rowp, int N) {
    __shared__ int swave[16];
    __shared__ int s_carry;
    int tid = threadIdx.x;
    int w = tid >> 6, lane = tid & 63;
    if (tid == 0) { rowp[0] = 0; s_carry = 0; }
    __syncthreads();
    for (int base = 0; base < N; base += 1024) {
        int i = base + tid;
        int v = (i < N) ? deg[i] : 0;
        int sc = v;
#pragma unroll
        for (int off = 1; off < 64; off <<= 1) {
            int t = __shfl_up(sc, off, 64);
            if (lane >= off) sc += t;
        }
        if (lane == 63) swave[w] = sc;
        __syncthreads();
        if (w == 0) {
            int ws = (lane < 16) ? swave[lane] : 0;
#pragma unroll
            for (int off = 1; off < 16; off <<= 1) {
                int t = __shfl_up(ws, off, 64);
                if (lane >= off) ws += t;
            }
            if (lane < 16) swave[lane] = ws;
        }
        __syncthreads();
        int carry = s_carry;
        int wprev = (w > 0) ? swave[w - 1] : 0;
        int incl = carry + wprev + sc;
        if (i < N) rowp[i + 1] = incl;
        __syncthreads();
        if (tid == 1023) s_carry = incl;
        __syncthreads();
    }
}

__global__ void scatter_kernel(const int* __restrict__ src, const int* __restrict__ dst,
                               const int* __restrict__ rowp, int* __restrict__ cur,
                               int* __restrict__ col, int E) {
    int e = blockIdx.x * 256 + threadIdx.x;
    if (e < E) {
        int d = dst[e];
        int pos = rowp[d] + atomicAdd(&cur[d], 1);
        col[pos] = src[e];
    }
}

// fp32 B[K][N] -> bf16 BT_hi/lo [N][K]  (weights only; tiny buffers)
__global__ void splitT_kernel(const float* __restrict__ B, u16* __restrict__ hiT,
                              u16* __restrict__ loT, int K, int N) {
    int n = blockIdx.x * 16 + threadIdx.x;
    int k = blockIdx.y * 16 + threadIdx.y;
    if (n < N && k < K) {
        float v = B[(size_t)k * N + n];
        u16 h = f2bf(v);
        float r = v - bf2f(h);
        hiT[(size_t)n * K + k] = h;
        loT[(size_t)n * K + k] = f2bf(r);
    }
}

// ---------------- split-bf16 MFMA GEMM: C = A@B (+bias) ----------------
// A: fp32 [M][K], split hi/lo in-register during LDS staging.
// B: bf16 hi/lo transposed [N][K].
// Output: fp32 to Cf if non-null, else bf16 to Cb.
#define BM 128
#define BN 64
#define BK 32
#define LDA 40   // padded LDS row stride (bf16 elems)

__global__ __launch_bounds__(256) void gemm_mfma_split(const float* __restrict__ A,
                                                       const u16* __restrict__ BThi,
                                                       const u16* __restrict__ BTlo,
                                                       const float* __restrict__ bias,
                                                       float* __restrict__ Cf,
                                                       u16* __restrict__ Cb,
                                                       int M, int N, int K) {
    __shared__ __align__(16) u16 sAh[BM * LDA];
    __shared__ __align__(16) u16 sAl[BM * LDA];
    __shared__ __align__(16) u16 sBh[BN * LDA];
    __shared__ __align__(16) u16 sBl[BN * LDA];
    int tid = threadIdx.x;
    int wave = tid >> 6, lane = tid & 63;
    int m0 = blockIdx.y * BM, n0 = blockIdx.x * BN;
    int fm = lane & 15;
    int q = lane >> 4;

    float4v acc[2][4];
#pragma unroll
    for (int i = 0; i < 2; i++)
#pragma unroll
        for (int j = 0; j < 4; j++) acc[i][j] = (float4v){0.f, 0.f, 0.f, 0.f};

    const uint4 zero4 = {0u, 0u, 0u, 0u};

    for (int kc = 0; kc < K; kc += BK) {
#pragma unroll
        for (int j = 0; j < 2; j++) {
            int e = (tid + j * 256) * 8;
            int row = e >> 5, colk = e & 31;
            int gr = m0 + row;
            float va[8];
            if (gr < M) {
                float4 f0 = *(const float4*)&A[(size_t)gr * K + kc + colk];
                float4 f1 = *(const float4*)&A[(size_t)gr * K + kc + colk + 4];
                va[0] = f0.x; va[1] = f0.y; va[2] = f0.z; va[3] = f0.w;
                va[4] = f1.x; va[5] = f1.y; va[6] = f1.z; va[7] = f1.w;
            } else {
#pragma unroll
                for (int i = 0; i < 8; i++) va[i] = 0.f;
            }
            short8 vh, vl;
#pragma unroll
            for (int i = 0; i < 8; i++) {
                u16 h = f2bf(va[i]);
                vh[i] = (short)h;
                vl[i] = (short)f2bf(va[i] - bf2f(h));
            }
            *(short8*)&sAh[row * LDA + colk] = vh;
            *(short8*)&sAl[row * LDA + colk] = vl;
        }
        {
            int e = tid * 8;
            int nn = e >> 5, colk = e & 31;
            int gn = n0 + nn;
            uint4 vh = zero4, vl = zero4;
            if (gn < N) {
                vh = *(const uint4*)&BThi[(size_t)gn * K + kc + colk];
                vl = *(const uint4*)&BTlo[(size_t)gn * K + kc + colk];
            }
            *(uint4*)&sBh[nn * LDA + colk] = vh;
            *(uint4*)&sBl[nn * LDA + colk] = vl;
        }
        __syncthreads();

        short8 bh[4], bl[4];
#pragma unroll
        for (int ni = 0; ni < 4; ni++) {
            int nn = ni * 16 + fm;
            bh[ni] = *(const short8*)&sBh[nn * LDA + q * 8];
            bl[ni] = *(const short8*)&sBl[nn * LDA + q * 8];
        }
#pragma unroll
        for (int mi = 0; mi < 2; mi++) {
            int row = wave * 32 + mi * 16 + fm;
            short8 ah = *(const short8*)&sAh[row * LDA + q * 8];
            short8 al = *(const short8*)&sAl[row * LDA + q * 8];
#pragma unroll
            for (int ni = 0; ni < 4; ni++) {
                acc[mi][ni] = __builtin_amdgcn_mfma_f32_16x16x32_bf16(ah, bh[ni], acc[mi][ni], 0, 0, 0);
                acc[mi][ni] = __builtin_amdgcn_mfma_f32_16x16x32_bf16(ah, bl[ni], acc[mi][ni], 0, 0, 0);
                acc[mi][ni] = __builtin_amdgcn_mfma_f32_16x16x32_bf16(al, bh[ni], acc[mi][ni], 0, 0, 0);
            }
        }
        __syncthreads();
    }

#pragma unroll
    for (int mi = 0; mi < 2; mi++) {
#pragma unroll
        for (int ni = 0; ni < 4; ni++) {
            int colg = n0 + ni * 16 + fm;
            if (colg >= N) continue;
            float bv = bias ? bias[colg] : 0.f;
#pragma unroll
            for (int r = 0; r < 4; r++) {
                int rowg = m0 + wave * 32 + mi * 16 + q * 4 + r;
                if (rowg < M) {
                    float v = acc[mi][ni][r] + bv;
                    if (Cf) Cf[(size_t)rowg * N + colg] = v;
                    else    Cb[(size_t)rowg * N + colg] = f2bf(v);
                }
            }
        }
    }
}

// ---------------- per-node attention coefficients (bf16 xh) ----------------
__global__ __launch_bounds__(256) void alpha_kernel(const u16* __restrict__ xh,
                                                    const float* __restrict__ a_s,
                                                    const float* __restrict__ a_d,
                                                    float* __restrict__ as_o,
                                                    float* __restrict__ ad_o, int C) {
    int n = blockIdx.x;
    int w = threadIdx.x >> 6, lane = threadIdx.x & 63;
    const u16* row = xh + (size_t)n * 4 * C + (size_t)w * C;
    float ss = 0.f, sd = 0.f;
    for (int c = lane; c < C; c += 64) {
        float v = bf2f(row[c]);
        ss += v * a_s[w * C + c];
        sd += v * a_d[w * C + c];
    }
    for (int o = 32; o; o >>= 1) {
        ss += __shfl_xor(ss, o, 64);
        sd += __shfl_xor(sd, o, 64);
    }
    if (!lane) {
        as_o[n * 4 + w] = ss;
        ad_o[n * 4 + w] = sd;
    }
}

// ---------------- edge-softmax + aggregate, HC=256 (layers 1/2), bf16 xh ----------------
// res/out may alias (in-place residual).
__global__ __launch_bounds__(256) void agg_kernel_256(const u16* __restrict__ xh,
                                                      const int* __restrict__ rowp,
                                                      const int* __restrict__ col,
                                                      const float* __restrict__ asrc,
                                                      const float* __restrict__ adst,
                                                      const float* __restrict__ bias,
                                                      const float* res,
                                                      float* out) {
    int n = blockIdx.x, tid = threadIdx.x;
    int r0 = rowp[n], deg = rowp[n + 1] - r0;
    __shared__ float sm[4], srd[4];
    __shared__ int s_src[64];
    __shared__ float s_alpha[64][4];
    int w = tid >> 6, lane = tid & 63;
    float adn = adst[n * 4 + w];
    float m = -3.4e38f;
    for (int k = lane; k < deg; k += 64) {
        int s = col[r0 + k];
        m = fmaxf(m, lrelu(asrc[s * 4 + w] + adn));
    }
    for (int o = 32; o; o >>= 1) m = fmaxf(m, __shfl_xor(m, o, 64));
    float sum = 0.f;
    for (int k = lane; k < deg; k += 64) {
        int s = col[r0 + k];
        sum += expf(lrelu(asrc[s * 4 + w] + adn) - m);
    }
    for (int o = 32; o; o >>= 1) sum += __shfl_xor(sum, o, 64);
    if (!lane) { sm[w] = m; srd[w] = 1.f / (sum + 1e-16f); }
    __syncthreads();
    float acc = 0.f;
    int h = tid >> 6;
    for (int kb = 0; kb < deg; kb += 64) {
        int cn = min(64, deg - kb);
        __syncthreads();
        for (int idx = tid; idx < cn * 4; idx += 256) {
            int kk = idx >> 2, hh = idx & 3;
            int s = col[r0 + kb + kk];
            if (hh == 0) s_src[kk] = s;
            float l = lrelu(asrc[s * 4 + hh] + adst[n * 4 + hh]);
            s_alpha[kk][hh] = expf(l - sm[hh]) * srd[hh];
        }
        __syncthreads();
        for (int kk = 0; kk < cn; kk++) {
            acc += s_alpha[kk][h] * bf2f(xh[(size_t)s_src[kk] * HC12 + tid]);
        }
    }
    float v = acc + bias[tid] + res[(size_t)n * HC12 + tid];
    out[(size_t)n * HC12 + tid] = v > 0.f ? v : expm1f(v);
}

// ---------------- layer 3: HC=484 bf16 xh, mean heads + b3 + lin3 -> d_out ----------------
__global__ __launch_bounds__(256) void agg_out_kernel(const u16* __restrict__ xh,
                                                      const int* __restrict__ rowp,
                                                      const int* __restrict__ col,
                                                      const float* __restrict__ asrc,
                                                      const float* __restrict__ adst,
                                                      const float* __restrict__ b3,
                                                      const float* __restrict__ lin3,
                                                      float* __restrict__ out) {
    int n = blockIdx.x, tid = threadIdx.x;
    int r0 = rowp[n], deg = rowp[n + 1] - r0;
    __shared__ float sm[4], srd[4];
    __shared__ int s_src[64];
    __shared__ float s_alpha[64][4];
    __shared__ float sagg[HC3];
    int w = tid >> 6, lane = tid & 63;
    float adn = adst[n * 4 + w];
    float m = -3.4e38f;
    for (int k = lane; k < deg; k += 64) {
        int s = col[r0 + k];
        m = fmaxf(m, lrelu(asrc[s * 4 + w] + adn));
    }
    for (int o = 32; o; o >>= 1) m = fmaxf(m, __shfl_xor(m, o, 64));
    float sum = 0.f;
    for (int k = lane; k < deg; k += 64) {
        int s = col[r0 + k];
        sum += expf(lrelu(asrc[s * 4 + w] + adn) - m);
    }
    for (int o = 32; o; o >>= 1) sum += __shfl_xor(sum, o, 64);
    if (!lane) { sm[w] = m; srd[w] = 1.f / (sum + 1e-16f); }
    __syncthreads();
    int ch1 = tid + 256;
    bool has1 = ch1 < HC3;
    int h0 = tid >= 363 ? 3 : (tid >= 242 ? 2 : (tid >= 121 ? 1 : 0));
    int h1v = ch1 >= 363 ? 3 : 2;
    float acc0 = 0.f, acc1 = 0.f;
    for (int kb = 0; kb < deg; kb += 64) {
        int cn = min(64, deg - kb);
        __syncthreads();
        for (int idx = tid; idx < cn * 4; idx += 256) {
            int kk = idx >> 2, hh = idx & 3;
            int s = col[r0 + kb + kk];
            if (hh == 0) s_src[kk] = s;
            float l = lrelu(asrc[s * 4 + hh] + adst[n * 4 + hh]);
            s_alpha[kk][hh] = expf(l - sm[hh]) * srd[hh];
        }
        __syncthreads();
        for (int kk = 0; kk < cn; kk++) {
            const u16* row = xh + (size_t)s_src[kk] * HC3;
            acc0 += s_alpha[kk][h0] * bf2f(row[tid]);
            if (has1) acc1 += s_alpha[kk][h1v] * bf2f(row[ch1]);
        }
    }
    sagg[tid] = acc0;
    if (has1) sagg[ch1] = acc1;
    __syncthreads();
    if (tid < NCLS) {
        float o = 0.25f * (sagg[tid] + sagg[NCLS + tid] + sagg[2 * NCLS + tid] + sagg[3 * NCLS + tid])
                  + b3[tid] + lin3[(size_t)n * NCLS + tid];
        out[(size_t)n * NCLS + tid] = o;
    }
}

extern "C" void kernel_launch(void* const* d_in, const int* in_sizes, int n_in,
                              void* d_out, int out_size, void* d_ws, size_t ws_size,
                              hipStream_t stream) {
    const float* x   = (const float*)d_in[0];
    const int*   ei  = (const int*)d_in[1];
    const float* W1  = (const float*)d_in[2];
    const float* a1s = (const float*)d_in[3];
    const float* a1d = (const float*)d_in[4];
    const float* b1  = (const float*)d_in[5];
    const float* l1W = (const float*)d_in[6];
    const float* l1b = (const float*)d_in[7];
    const float* W2  = (const float*)d_in[8];
    const float* a2s = (const float*)d_in[9];
    const float* a2d = (const float*)d_in[10];
    const float* b2  = (const float*)d_in[11];
    const float* W3  = (const float*)d_in[12];
    const float* a3s = (const float*)d_in[13];
    const float* a3d = (const float*)d_in[14];
    const float* b3  = (const float*)d_in[15];
    const float* l3W = (const float*)d_in[16];
    const float* l3b = (const float*)d_in[17];

    const int N = in_sizes[0] / F_IN;   // 50000
    const int E = in_sizes[1] / 2;      // 400000
    const int* srcv = ei;
    const int* dstv = ei + E;

    char* ws = (char*)d_ws;
    size_t off = 0;
    auto alloc = [&](size_t bytes) -> char* {
        char* p = ws + off;
        off += (bytes + 255) & ~(size_t)255;
        return p;
    };
    u16*   xh   = (u16*)alloc((size_t)N * HC3 * 2);      // bf16 GEMM outputs
    float* h1   = (float*)alloc((size_t)N * HC12 * 4);
    float* h2   = (float*)alloc((size_t)N * HC12 * 4);
    float* lin  = (float*)alloc((size_t)N * NCLS * 4);
    float* as_  = (float*)alloc((size_t)N * 4 * 4);
    float* ad_  = (float*)alloc((size_t)N * 4 * 4);
    int* rowp   = (int*)alloc((size_t)(N + 1) * 4);
    int* degc   = (int*)alloc((size_t)N * 4);
    int* cur    = (int*)alloc((size_t)N * 4);
    int* col    = (int*)alloc((size_t)E * 4);
    u16* W1T_h  = (u16*)alloc((size_t)HC12 * F_IN * 2);
    u16* W1T_l  = (u16*)alloc((size_t)HC12 * F_IN * 2);
    u16* L1T_h  = (u16*)alloc((size_t)HC12 * F_IN * 2);
    u16* L1T_l  = (u16*)alloc((size_t)HC12 * F_IN * 2);
    u16* W2T_h  = (u16*)alloc((size_t)HC12 * HC12 * 2);
    u16* W2T_l  = (u16*)alloc((size_t)HC12 * HC12 * 2);
    u16* W3T_h  = (u16*)alloc((size_t)HC3 * HC12 * 2);
    u16* W3T_l  = (u16*)alloc((size_t)HC3 * HC12 * 2);
    u16* L3T_h  = (u16*)alloc((size_t)NCLS * HC12 * 2);
    u16* L3T_l  = (u16*)alloc((size_t)NCLS * HC12 * 2);
    (void)ws_size; (void)n_in; (void)out_size;

    // ---- CSR build ----
    hipMemsetAsync(degc, 0, (size_t)N * 4, stream);
    hipMemsetAsync(cur, 0, (size_t)N * 4, stream);
    hist_kernel<<<(E + 255) / 256, 256, 0, stream>>>(dstv, degc, E);
    scan_kernel<<<1, 1024, 0, stream>>>(degc, rowp, N);
    scatter_kernel<<<(E + 255) / 256, 256, 0, stream>>>(srcv, dstv, rowp, cur, col, E);

    // ---- weight splits (transposed) ----
    dim3 tb(16, 16);
    splitT_kernel<<<dim3((HC12 + 15) / 16, (F_IN + 15) / 16), tb, 0, stream>>>(W1, W1T_h, W1T_l, F_IN, HC12);
    splitT_kernel<<<dim3((HC12 + 15) / 16, (F_IN + 15) / 16), tb, 0, stream>>>(l1W, L1T_h, L1T_l, F_IN, HC12);
    splitT_kernel<<<dim3((HC12 + 15) / 16, (HC12 + 15) / 16), tb, 0, stream>>>(W2, W2T_h, W2T_l, HC12, HC12);
    splitT_kernel<<<dim3((HC3 + 15) / 16, (HC12 + 15) / 16), tb, 0, stream>>>(W3, W3T_h, W3T_l, HC12, HC3);
    splitT_kernel<<<dim3((NCLS + 15) / 16, (HC12 + 15) / 16), tb, 0, stream>>>(l3W, L3T_h, L3T_l, HC12, NCLS);

    int mgrid = (N + BM - 1) / BM;

    // ---- layer 1 ----
    gemm_mfma_split<<<dim3(4, mgrid), 256, 0, stream>>>(x, W1T_h, W1T_l, nullptr, nullptr, xh, N, HC12, F_IN);
    gemm_mfma_split<<<dim3(4, mgrid), 256, 0, stream>>>(x, L1T_h, L1T_l, l1b, h1, nullptr, N, HC12, F_IN);
    alpha_kernel<<<N, 256, 0, stream>>>(xh, a1s, a1d, as_, ad_, 64);
    agg_kernel_256<<<N, 256, 0, stream>>>(xh, rowp, col, as_, ad_, b1, h1, h1);  // in-place residual

    // ---- layer 2 ----
    gemm_mfma_split<<<dim3(4, mgrid), 256, 0, stream>>>(h1, W2T_h, W2T_l, nullptr, nullptr, xh, N, HC12, HC12);
    alpha_kernel<<<N, 256, 0, stream>>>(xh, a2s, a2d, as_, ad_, 64);
    agg_kernel_256<<<N, 256, 0, stream>>>(xh, rowp, col, as_, ad_, b2, h1, h2);

    // ---- layer 3 ----
    gemm_mfma_split<<<dim3(8, mgrid), 256, 0, stream>>>(h2, W3T_h, W3T_l, nullptr, nullptr, xh, N, HC3, HC12);
    gemm_mfma_split<<<dim3(2, mgrid), 256, 0, stream>>>(h2, L3T_h, L3T_l, l3b, lin, nullptr, N, NCLS, HC12);
    alpha_kernel<<<N, 256, 0, stream>>>(xh, a3s, a3d, as_, ad_, NCLS);
    agg_out_kernel<<<N, 256, 0, stream>>>(xh, rowp, col, as_, ad_, b3, lin, (float*)d_out);
}

// Round 5
// 807.871 us; speedup vs baseline: 1.8180x; 1.1714x over previous
//
#include <hip/hip_runtime.h>
#include <cstdint>
#include <cstddef>

#define F_IN 128
#define HC12 256   // HEADS*HID for layers 1/2
#define HC3 484    // OUT_HEADS*N_CLS for layer 3
#define NCLS 121

typedef unsigned short u16;
typedef unsigned int u32;
typedef __attribute__((ext_vector_type(8))) short short8;
typedef __attribute__((ext_vector_type(4))) float float4v;

static __device__ __forceinline__ float lrelu(float x) { return x > 0.f ? x : 0.2f * x; }

static __device__ __forceinline__ u16 f2bf(float f) {
    union { float f; unsigned u; } v; v.f = f;
    unsigned r = v.u + 0x7FFF + ((v.u >> 16) & 1);
    return (u16)(r >> 16);
}
static __device__ __forceinline__ float bf2f(u16 h) {
    union { unsigned u; float f; } v; v.u = ((unsigned)h) << 16;
    return v.f;
}

// ---------------- CSR build ----------------
__global__ void hist_kernel(const int* __restrict__ dst, int* __restrict__ deg, int E) {
    int e = blockIdx.x * 256 + threadIdx.x;
    if (e < E) atomicAdd(&deg[dst[e]], 1);
}

// shfl-based scan: 2 barriers per 1024-chunk
__global__ __launch_bounds__(1024) void scan_kernel(const int* __restrict__ deg,
                                                    int* __restrict__ rowp, int N) {
    __shared__ int swave[16];
    __shared__ int s_carry;
    int tid = threadIdx.x;
    int w = tid >> 6, lane = tid & 63;
    if (tid == 0) { rowp[0] = 0; s_carry = 0; }
    __syncthreads();
    for (int base = 0; base < N; base += 1024) {
        int i = base + tid;
        int v = (i < N) ? deg[i] : 0;
        int sc = v;
#pragma unroll
        for (int off = 1; off < 64; off <<= 1) {
            int t = __shfl_up(sc, off, 64);
            if (lane >= off) sc += t;
        }
        if (lane == 63) swave[w] = sc;
        __syncthreads();
        if (w == 0) {
            int ws = (lane < 16) ? swave[lane] : 0;
#pragma unroll
            for (int off = 1; off < 16; off <<= 1) {
                int t = __shfl_up(ws, off, 64);
                if (lane >= off) ws += t;
            }
            if (lane < 16) swave[lane] = ws;
        }
        __syncthreads();
        int carry = s_carry;
        int wprev = (w > 0) ? swave[w - 1] : 0;
        int incl = carry + wprev + sc;
        if (i < N) rowp[i + 1] = incl;
        __syncthreads();
        if (tid == 1023) s_carry = incl;
        __syncthreads();
    }
}

__global__ void scatter_kernel(const int* __restrict__ src, const int* __restrict__ dst,
                               const int* __restrict__ rowp, int* __restrict__ cur,
                               int* __restrict__ col, int* __restrict__ dstE, int E) {
    int e = blockIdx.x * 256 + threadIdx.x;
    if (e < E) {
        int d = dst[e];
        int pos = rowp[d] + atomicAdd(&cur[d], 1);
        col[pos] = src[e];
        dstE[pos] = d;
    }
}

// fp32 B[K][N] -> bf16 BT_hi/lo [N][K]
__global__ void splitT_kernel(const float* __restrict__ B, u16* __restrict__ hiT,
                              u16* __restrict__ loT, int K, int N) {
    int n = blockIdx.x * 16 + threadIdx.x;
    int k = blockIdx.y * 16 + threadIdx.y;
    if (n < N && k < K) {
        float v = B[(size_t)k * N + n];
        u16 h = f2bf(v);
        float r = v - bf2f(h);
        hiT[(size_t)n * K + k] = h;
        loT[(size_t)n * K + k] = f2bf(r);
    }
}

// ---------------- split-bf16 MFMA GEMM (same as R4) ----------------
#define BM 128
#define BN 64
#define BK 32
#define LDA 40

__global__ __launch_bounds__(256) void gemm_mfma_split(const float* __restrict__ A,
                                                       const u16* __restrict__ BThi,
                                                       const u16* __restrict__ BTlo,
                                                       const float* __restrict__ bias,
                                                       float* __restrict__ Cf,
                                                       u16* __restrict__ Cb,
                                                       int M, int N, int K) {
    __shared__ __align__(16) u16 sAh[BM * LDA];
    __shared__ __align__(16) u16 sAl[BM * LDA];
    __shared__ __align__(16) u16 sBh[BN * LDA];
    __shared__ __align__(16) u16 sBl[BN * LDA];
    int tid = threadIdx.x;
    int wave = tid >> 6, lane = tid & 63;
    int m0 = blockIdx.y * BM, n0 = blockIdx.x * BN;
    int fm = lane & 15;
    int q = lane >> 4;

    float4v acc[2][4];
#pragma unroll
    for (int i = 0; i < 2; i++)
#pragma unroll
        for (int j = 0; j < 4; j++) acc[i][j] = (float4v){0.f, 0.f, 0.f, 0.f};

    const uint4 zero4 = {0u, 0u, 0u, 0u};

    for (int kc = 0; kc < K; kc += BK) {
#pragma unroll
        for (int j = 0; j < 2; j++) {
            int e = (tid + j * 256) * 8;
            int row = e >> 5, colk = e & 31;
            int gr = m0 + row;
            float va[8];
            if (gr < M) {
                float4 f0 = *(const float4*)&A[(size_t)gr * K + kc + colk];
                float4 f1 = *(const float4*)&A[(size_t)gr * K + kc + colk + 4];
                va[0] = f0.x; va[1] = f0.y; va[2] = f0.z; va[3] = f0.w;
                va[4] = f1.x; va[5] = f1.y; va[6] = f1.z; va[7] = f1.w;
            } else {
#pragma unroll
                for (int i = 0; i < 8; i++) va[i] = 0.f;
            }
            short8 vh, vl;
#pragma unroll
            for (int i = 0; i < 8; i++) {
                u16 h = f2bf(va[i]);
                vh[i] = (short)h;
                vl[i] = (short)f2bf(va[i] - bf2f(h));
            }
            *(short8*)&sAh[row * LDA + colk] = vh;
            *(short8*)&sAl[row * LDA + colk] = vl;
        }
        {
            int e = tid * 8;
            int nn = e >> 5, colk = e & 31;
            int gn = n0 + nn;
            uint4 vh = zero4, vl = zero4;
            if (gn < N) {
                vh = *(const uint4*)&BThi[(size_t)gn * K + kc + colk];
                vl = *(const uint4*)&BTlo[(size_t)gn * K + kc + colk];
            }
            *(uint4*)&sBh[nn * LDA + colk] = vh;
            *(uint4*)&sBl[nn * LDA + colk] = vl;
        }
        __syncthreads();

        short8 bh[4], bl[4];
#pragma unroll
        for (int ni = 0; ni < 4; ni++) {
            int nn = ni * 16 + fm;
            bh[ni] = *(const short8*)&sBh[nn * LDA + q * 8];
            bl[ni] = *(const short8*)&sBl[nn * LDA + q * 8];
        }
#pragma unroll
        for (int mi = 0; mi < 2; mi++) {
            int row = wave * 32 + mi * 16 + fm;
            short8 ah = *(const short8*)&sAh[row * LDA + q * 8];
            short8 al = *(const short8*)&sAl[row * LDA + q * 8];
#pragma unroll
            for (int ni = 0; ni < 4; ni++) {
                acc[mi][ni] = __builtin_amdgcn_mfma_f32_16x16x32_bf16(ah, bh[ni], acc[mi][ni], 0, 0, 0);
                acc[mi][ni] = __builtin_amdgcn_mfma_f32_16x16x32_bf16(ah, bl[ni], acc[mi][ni], 0, 0, 0);
                acc[mi][ni] = __builtin_amdgcn_mfma_f32_16x16x32_bf16(al, bh[ni], acc[mi][ni], 0, 0, 0);
            }
        }
        __syncthreads();
    }

#pragma unroll
    for (int mi = 0; mi < 2; mi++) {
#pragma unroll
        for (int ni = 0; ni < 4; ni++) {
            int colg = n0 + ni * 16 + fm;
            if (colg >= N) continue;
            float bv = bias ? bias[colg] : 0.f;
#pragma unroll
            for (int r = 0; r < 4; r++) {
                int rowg = m0 + wave * 32 + mi * 16 + q * 4 + r;
                if (rowg < M) {
                    float v = acc[mi][ni][r] + bv;
                    if (Cf) Cf[(size_t)rowg * N + colg] = v;
                    else    Cb[(size_t)rowg * N + colg] = f2bf(v);
                }
            }
        }
    }
}

// ---------------- per-node attention coefficients (bf16 xh) ----------------
__global__ __launch_bounds__(256) void alpha_kernel(const u16* __restrict__ xh,
                                                    const float* __restrict__ a_s,
                                                    const float* __restrict__ a_d,
                                                    float* __restrict__ as_o,
                                                    float* __restrict__ ad_o, int C) {
    int n = blockIdx.x;
    int w = threadIdx.x >> 6, lane = threadIdx.x & 63;
    const u16* row = xh + (size_t)n * 4 * C + (size_t)w * C;
    float ss = 0.f, sd = 0.f;
    for (int c = lane; c < C; c += 64) {
        float v = bf2f(row[c]);
        ss += v * a_s[w * C + c];
        sd += v * a_d[w * C + c];
    }
    for (int o = 32; o; o >>= 1) {
        ss += __shfl_xor(ss, o, 64);
        sd += __shfl_xor(sd, o, 64);
    }
    if (!lane) {
        as_o[n * 4 + w] = ss;
        ad_o[n * 4 + w] = sd;
    }
}

// ---------------- per-(node,head) online-softmax stats ----------------
__global__ __launch_bounds__(256) void stats_kernel(const int* __restrict__ rowp,
                                                    const int* __restrict__ col,
                                                    const float* __restrict__ asrc,
                                                    const float* __restrict__ adst,
                                                    float* __restrict__ m_o,
                                                    float* __restrict__ rd_o, int N) {
    int i = blockIdx.x * 256 + threadIdx.x;
    if (i >= N * 4) return;
    int n = i >> 2, h = i & 3;
    int r0 = rowp[n], r1 = rowp[n + 1];
    float ad = adst[i];
    float m = -3.4e38f, s = 0.f;
    for (int e = r0; e < r1; e++) {
        int sc = col[e];
        float l = lrelu(asrc[sc * 4 + h] + ad);
        float nm = fmaxf(m, l);
        s = s * __expf(m - nm) + __expf(l - nm);
        m = nm;
    }
    m_o[i] = m;
    rd_o[i] = 1.f / (s + 1e-16f);
}

// ---------------- per-edge alpha ----------------
__global__ __launch_bounds__(256) void edge_alpha_kernel(const int* __restrict__ col,
                                                         const int* __restrict__ dstE,
                                                         const float* __restrict__ asrc,
                                                         const float* __restrict__ adst,
                                                         const float* __restrict__ m_,
                                                         const float* __restrict__ rd_,
                                                         float* __restrict__ alphaE, int E) {
    int i = blockIdx.x * 256 + threadIdx.x;
    if (i >= E * 4) return;
    int e = i >> 2, h = i & 3;
    int sc = col[e], d = dstE[e];
    float l = lrelu(asrc[sc * 4 + h] + adst[d * 4 + h]);
    alphaE[i] = __expf(l - m_[d * 4 + h]) * rd_[d * 4 + h];
}

// ---------------- gather+FMA aggregate, HC=256 (layers 1/2) ----------------
// res/out may alias (in-place residual).
__global__ __launch_bounds__(256) void agg_kernel_256(const u16* __restrict__ xh,
                                                      const int* __restrict__ rowp,
                                                      const int* __restrict__ col,
                                                      const float* __restrict__ alphaE,
                                                      const float* __restrict__ bias,
                                                      const float* res,
                                                      float* out) {
    int n = blockIdx.x, tid = threadIdx.x;
    int r0 = rowp[n], deg = rowp[n + 1] - r0;
    __shared__ int s_src[64];
    __shared__ float s_al[64][4];
    __shared__ float s_part[2][HC12];
    int g = tid >> 7;          // edge group (0/1)
    int sub = tid & 127;
    int c = sub * 2;           // channel pair
    int h = sub >> 5;          // c/64
    float a0 = 0.f, a1 = 0.f;
    for (int kb = 0; kb < deg; kb += 64) {
        int cn = min(64, deg - kb);
        __syncthreads();
        if (tid < cn) s_src[tid] = col[r0 + kb + tid];
        for (int idx = tid; idx < cn * 4; idx += 256)
            s_al[idx >> 2][idx & 3] = alphaE[(size_t)(r0 + kb) * 4 + idx];
        __syncthreads();
#pragma unroll 4
        for (int kk = g; kk < cn; kk += 2) {
            u32 v = *(const u32*)&xh[(size_t)s_src[kk] * HC12 + c];
            float al = s_al[kk][h];
            a0 += al * bf2f((u16)(v & 0xffff));
            a1 += al * bf2f((u16)(v >> 16));
        }
    }
    s_part[g][c] = a0;
    s_part[g][c + 1] = a1;
    __syncthreads();
    float v = s_part[0][tid] + s_part[1][tid] + bias[tid] + res[(size_t)n * HC12 + tid];
    out[(size_t)n * HC12 + tid] = v > 0.f ? v : expm1f(v);
}

// ---------------- layer 3 gather: HC=484, mean heads + b3 + lin3 -> d_out ----------------
__global__ __launch_bounds__(256) void agg_out_kernel(const u16* __restrict__ xh,
                                                      const int* __restrict__ rowp,
                                                      const int* __restrict__ col,
                                                      const float* __restrict__ alphaE,
                                                      const float* __restrict__ b3,
                                                      const float* __restrict__ lin3,
                                                      float* __restrict__ out) {
    int n = blockIdx.x, tid = threadIdx.x;
    int r0 = rowp[n], deg = rowp[n + 1] - r0;
    __shared__ int s_src[64];
    __shared__ float s_al[64][4];
    __shared__ float s_out[HC3];
    bool act = tid < 242;                 // 242 * 2 = 484 channels
    int c0 = 2 * tid, c1 = c0 + 1;
    int h0 = c0 >= 363 ? 3 : (c0 >= 242 ? 2 : (c0 >= 121 ? 1 : 0));
    int h1 = c1 >= 363 ? 3 : (c1 >= 242 ? 2 : (c1 >= 121 ? 1 : 0));
    float a0 = 0.f, a1 = 0.f;
    for (int kb = 0; kb < deg; kb += 64) {
        int cn = min(64, deg - kb);
        __syncthreads();
        if (tid < cn) s_src[tid] = col[r0 + kb + tid];
        for (int idx = tid; idx < cn * 4; idx += 256)
            s_al[idx >> 2][idx & 3] = alphaE[(size_t)(r0 + kb) * 4 + idx];
        __syncthreads();
        if (act) {
#pragma unroll 4
            for (int kk = 0; kk < cn; kk++) {
                u32 v = *(const u32*)&xh[(size_t)s_src[kk] * HC3 + c0];
                a0 += s_al[kk][h0] * bf2f((u16)(v & 0xffff));
                a1 += s_al[kk][h1] * bf2f((u16)(v >> 16));
            }
        }
    }
    if (act) { s_out[c0] = a0; s_out[c1] = a1; }
    __syncthreads();
    if (tid < NCLS) {
        float o = 0.25f * (s_out[tid] + s_out[NCLS + tid] + s_out[2 * NCLS + tid] + s_out[3 * NCLS + tid])
                  + b3[tid] + lin3[(size_t)n * NCLS + tid];
        out[(size_t)n * NCLS + tid] = o;
    }
}

extern "C" void kernel_launch(void* const* d_in, const int* in_sizes, int n_in,
                              void* d_out, int out_size, void* d_ws, size_t ws_size,
                              hipStream_t stream) {
    const float* x   = (const float*)d_in[0];
    const int*   ei  = (const int*)d_in[1];
    const float* W1  = (const float*)d_in[2];
    const float* a1s = (const float*)d_in[3];
    const float* a1d = (const float*)d_in[4];
    const float* b1  = (const float*)d_in[5];
    const float* l1W = (const float*)d_in[6];
    const float* l1b = (const float*)d_in[7];
    const float* W2  = (const float*)d_in[8];
    const float* a2s = (const float*)d_in[9];
    const float* a2d = (const float*)d_in[10];
    const float* b2  = (const float*)d_in[11];
    const float* W3  = (const float*)d_in[12];
    const float* a3s = (const float*)d_in[13];
    const float* a3d = (const float*)d_in[14];
    const float* b3  = (const float*)d_in[15];
    const float* l3W = (const float*)d_in[16];
    const float* l3b = (const float*)d_in[17];

    const int N = in_sizes[0] / F_IN;   // 50000
    const int E = in_sizes[1] / 2;      // 400000
    const int* srcv = ei;
    const int* dstv = ei + E;

    char* ws = (char*)d_ws;
    size_t off = 0;
    auto alloc = [&](size_t bytes) -> char* {
        char* p = ws + off;
        off += (bytes + 255) & ~(size_t)255;
        return p;
    };
    u16*   xh   = (u16*)alloc((size_t)N * HC3 * 2);
    float* h1   = (float*)alloc((size_t)N * HC12 * 4);
    float* h2   = (float*)alloc((size_t)N * HC12 * 4);
    float* lin  = (float*)alloc((size_t)N * NCLS * 4);
    float* as_  = (float*)alloc((size_t)N * 4 * 4);
    float* ad_  = (float*)alloc((size_t)N * 4 * 4);
    float* m_   = (float*)alloc((size_t)N * 4 * 4);
    float* rd_  = (float*)alloc((size_t)N * 4 * 4);
    int* rowp   = (int*)alloc((size_t)(N + 1) * 4);
    int* degc   = (int*)alloc((size_t)N * 4);
    int* cur    = (int*)alloc((size_t)N * 4);
    int* col    = (int*)alloc((size_t)E * 4);
    int* dstE   = (int*)alloc((size_t)E * 4);
    float* alphaE = (float*)alloc((size_t)E * 4 * 4);
    u16* W1T_h  = (u16*)alloc((size_t)HC12 * F_IN * 2);
    u16* W1T_l  = (u16*)alloc((size_t)HC12 * F_IN * 2);
    u16* L1T_h  = (u16*)alloc((size_t)HC12 * F_IN * 2);
    u16* L1T_l  = (u16*)alloc((size_t)HC12 * F_IN * 2);
    u16* W2T_h  = (u16*)alloc((size_t)HC12 * HC12 * 2);
    u16* W2T_l  = (u16*)alloc((size_t)HC12 * HC12 * 2);
    u16* W3T_h  = (u16*)alloc((size_t)HC3 * HC12 * 2);
    u16* W3T_l  = (u16*)alloc((size_t)HC3 * HC12 * 2);
    u16* L3T_h  = (u16*)alloc((size_t)NCLS * HC12 * 2);
    u16* L3T_l  = (u16*)alloc((size_t)NCLS * HC12 * 2);
    (void)ws_size; (void)n_in; (void)out_size;

    // ---- CSR build ----
    hipMemsetAsync(degc, 0, (size_t)N * 4, stream);
    hipMemsetAsync(cur, 0, (size_t)N * 4, stream);
    hist_kernel<<<(E + 255) / 256, 256, 0, stream>>>(dstv, degc, E);
    scan_kernel<<<1, 1024, 0, stream>>>(degc, rowp, N);
    scatter_kernel<<<(E + 255) / 256, 256, 0, stream>>>(srcv, dstv, rowp, cur, col, dstE, E);

    // ---- weight splits (transposed) ----
    dim3 tb(16, 16);
    splitT_kernel<<<dim3((HC12 + 15) / 16, (F_IN + 15) / 16), tb, 0, stream>>>(W1, W1T_h, W1T_l, F_IN, HC12);
    splitT_kernel<<<dim3((HC12 + 15) / 16, (F_IN + 15) / 16), tb, 0, stream>>>(l1W, L1T_h, L1T_l, F_IN, HC12);
    splitT_kernel<<<dim3((HC12 + 15) / 16, (HC12 + 15) / 16), tb, 0, stream>>>(W2, W2T_h, W2T_l, HC12, HC12);
    splitT_kernel<<<dim3((HC3 + 15) / 16, (HC12 + 15) / 16), tb, 0, stream>>>(W3, W3T_h, W3T_l, HC12, HC3);
    splitT_kernel<<<dim3((NCLS + 15) / 16, (HC12 + 15) / 16), tb, 0, stream>>>(l3W, L3T_h, L3T_l, HC12, NCLS);

    int mgrid = (N + BM - 1) / BM;
    int sgrid = (N * 4 + 255) / 256;
    int egrid = (E * 4 + 255) / 256;

    // ---- layer 1 ----
    gemm_mfma_split<<<dim3(4, mgrid), 256, 0, stream>>>(x, W1T_h, W1T_l, nullptr, nullptr, xh, N, HC12, F_IN);
    gemm_mfma_split<<<dim3(4, mgrid), 256, 0, stream>>>(x, L1T_h, L1T_l, l1b, h1, nullptr, N, HC12, F_IN);
    alpha_kernel<<<N, 256, 0, stream>>>(xh, a1s, a1d, as_, ad_, 64);
    stats_kernel<<<sgrid, 256, 0, stream>>>(rowp, col, as_, ad_, m_, rd_, N);
    edge_alpha_kernel<<<egrid, 256, 0, stream>>>(col, dstE, as_, ad_, m_, rd_, alphaE, E);
    agg_kernel_256<<<N, 256, 0, stream>>>(xh, rowp, col, alphaE, b1, h1, h1);  // in-place residual

    // ---- layer 2 ----
    gemm_mfma_split<<<dim3(4, mgrid), 256, 0, stream>>>(h1, W2T_h, W2T_l, nullptr, nullptr, xh, N, HC12, HC12);
    alpha_kernel<<<N, 256, 0, stream>>>(xh, a2s, a2d, as_, ad_, 64);
    stats_kernel<<<sgrid, 256, 0, stream>>>(rowp, col, as_, ad_, m_, rd_, N);
    edge_alpha_kernel<<<egrid, 256, 0, stream>>>(col, dstE, as_, ad_, m_, rd_, alphaE, E);
    agg_kernel_256<<<N, 256, 0, stream>>>(xh, rowp, col, alphaE, b2, h1, h2);

    // ---- layer 3 ----
    gemm_mfma_split<<<dim3(8, mgrid), 256, 0, stream>>>(h2, W3T_h, W3T_l, nullptr, nullptr, xh, N, HC3, HC12);
    gemm_mfma_split<<<dim3(2, mgrid), 256, 0, stream>>>(h2, L3T_h, L3T_l, l3b, lin, nullptr, N, NCLS, HC12);
    alpha_kernel<<<N, 256, 0, stream>>>(xh, a3s, a3d, as_, ad_, NCLS);
    stats_kernel<<<sgrid, 256, 0, stream>>>(rowp, col, as_, ad_, m_, rd_, N);
    edge_alpha_kernel<<<egrid, 256, 0, stream>>>(col, dstE, as_, ad_, m_, rd_, alphaE, E);
    agg_out_kernel<<<N, 256, 0, stream>>>(xh, rowp, col, alphaE, b3, lin, (float*)d_out);
}

// Round 6
// 760.000 us; speedup vs baseline: 1.9325x; 1.0630x over previous
//
#include <hip/hip_runtime.h>
#include <cstdint>
#include <cstddef>

#define F_IN 128
#define HC12 256   // HEADS*HID for layers 1/2
#define HC3 484    // OUT_HEADS*N_CLS for layer 3
#define NCLS 121

typedef unsigned short u16;
typedef unsigned int u32;
typedef __attribute__((ext_vector_type(8))) short short8;
typedef __attribute__((ext_vector_type(4))) float float4v;

static __device__ __forceinline__ float lrelu(float x) { return x > 0.f ? x : 0.2f * x; }

static __device__ __forceinline__ u16 f2bf(float f) {
    union { float f; unsigned u; } v; v.f = f;
    unsigned r = v.u + 0x7FFF + ((v.u >> 16) & 1);
    return (u16)(r >> 16);
}
static __device__ __forceinline__ float bf2f(u16 h) {
    union { unsigned u; float f; } v; v.u = ((unsigned)h) << 16;
    return v.f;
}

// ---------------- CSR build ----------------
__global__ void hist_kernel(const int* __restrict__ dst, int* __restrict__ deg, int E) {
    int e = blockIdx.x * 256 + threadIdx.x;
    if (e < E) atomicAdd(&deg[dst[e]], 1);
}

__global__ __launch_bounds__(1024) void scan_kernel(const int* __restrict__ deg,
                                                    int* __restrict__ rowp, int N) {
    __shared__ int swave[16];
    __shared__ int s_carry;
    int tid = threadIdx.x;
    int w = tid >> 6, lane = tid & 63;
    if (tid == 0) { rowp[0] = 0; s_carry = 0; }
    __syncthreads();
    for (int base = 0; base < N; base += 1024) {
        int i = base + tid;
        int v = (i < N) ? deg[i] : 0;
        int sc = v;
#pragma unroll
        for (int off = 1; off < 64; off <<= 1) {
            int t = __shfl_up(sc, off, 64);
            if (lane >= off) sc += t;
        }
        if (lane == 63) swave[w] = sc;
        __syncthreads();
        if (w == 0) {
            int ws = (lane < 16) ? swave[lane] : 0;
#pragma unroll
            for (int off = 1; off < 16; off <<= 1) {
                int t = __shfl_up(ws, off, 64);
                if (lane >= off) ws += t;
            }
            if (lane < 16) swave[lane] = ws;
        }
        __syncthreads();
        int carry = s_carry;
        int wprev = (w > 0) ? swave[w - 1] : 0;
        int incl = carry + wprev + sc;
        if (i < N) rowp[i + 1] = incl;
        __syncthreads();
        if (tid == 1023) s_carry = incl;
        __syncthreads();
    }
}

__global__ void scatter_kernel(const int* __restrict__ src, const int* __restrict__ dst,
                               const int* __restrict__ rowp, int* __restrict__ cur,
                               int* __restrict__ col, int* __restrict__ dstE, int E) {
    int e = blockIdx.x * 256 + threadIdx.x;
    if (e < E) {
        int d = dst[e];
        int pos = rowp[d] + atomicAdd(&cur[d], 1);
        col[pos] = src[e];
        dstE[pos] = d;
    }
}

// ---------------- fused weight split+transpose (all 5 matrices, 1 launch) ----------------
// segment s: B[K][N] fp32 -> hiT/loT [N][K] bf16 at given dst offsets
struct WSeg { const float* B; u16* hi; u16* lo; int K; int N; int cnt; };

__global__ void splitT_all_kernel(const float* W1, const float* l1W, const float* W2,
                                  const float* W3, const float* l3W,
                                  u16* C1h, u16* C1l, u16* C2h, u16* C2l,
                                  u16* C3h, u16* C3l) {
    int i = blockIdx.x * 256 + threadIdx.x;
    const float* B; u16* hi; u16* lo; int K, N;
    // segment sizes: W1 128*256=32768 -> C1 rows 0..255
    //                l1W 32768        -> C1 rows 256..511
    //                W2 256*256=65536 -> C2
    //                W3 256*484=123904-> C3 rows 0..483
    //                l3W 256*121=30976-> C3 rows 484..604
    if (i < 32768)       { B = W1;  hi = C1h;             lo = C1l;             K = 128; N = 256; }
    else if (i < 65536)  { B = l1W; hi = C1h + 256 * 128; lo = C1l + 256 * 128; K = 128; N = 256; i -= 32768; }
    else if (i < 131072) { B = W2;  hi = C2h;             lo = C2l;             K = 256; N = 256; i -= 65536; }
    else if (i < 254976) { B = W3;  hi = C3h;             lo = C3l;             K = 256; N = 484; i -= 131072; }
    else if (i < 285952) { B = l3W; hi = C3h + 484 * 256; lo = C3l + 484 * 256; K = 256; N = 121; i -= 254976; }
    else return;
    int n = i % N, k = i / N;
    float v = B[(size_t)k * N + n];
    u16 h = f2bf(v);
    hi[(size_t)n * K + k] = h;
    lo[(size_t)n * K + k] = f2bf(v - bf2f(h));
}

// ---------------- split-bf16 MFMA GEMM, 128x128 tile, dual-destination epilogue -------
// A: fp32 [M][K] (hi/lo split in-register during staging)
// BT: bf16 hi/lo [Ntot][K]
// cols [0,Nb)   -> bf16 Cb (stride strideB)
// cols [Nb,Ntot)-> fp32 Cf + biasf (stride strideF)
#define BM 128
#define BN 128
#define BK 32
#define LDA 40

__global__ __launch_bounds__(256) void gemm_mfma_split(const float* __restrict__ A,
                                                       const u16* __restrict__ BThi,
                                                       const u16* __restrict__ BTlo,
                                                       int M, int K, int Ntot,
                                                       int Nb, u16* __restrict__ Cb, int strideB,
                                                       float* __restrict__ Cf,
                                                       const float* __restrict__ biasf, int strideF) {
    __shared__ __align__(16) u16 sAh[BM * LDA];
    __shared__ __align__(16) u16 sAl[BM * LDA];
    __shared__ __align__(16) u16 sBh[BN * LDA];
    __shared__ __align__(16) u16 sBl[BN * LDA];
    int tid = threadIdx.x;
    int wave = tid >> 6, lane = tid & 63;
    int m0 = blockIdx.y * BM, n0 = blockIdx.x * BN;
    int fm = lane & 15;
    int q = lane >> 4;

    float4v acc[2][8];
#pragma unroll
    for (int i = 0; i < 2; i++)
#pragma unroll
        for (int j = 0; j < 8; j++) acc[i][j] = (float4v){0.f, 0.f, 0.f, 0.f};

    const uint4 zero4 = {0u, 0u, 0u, 0u};

    for (int kc = 0; kc < K; kc += BK) {
        // stage A: 128x32 fp32 -> hi/lo bf16 (16 elems/thread)
#pragma unroll
        for (int j = 0; j < 2; j++) {
            int e = (tid + j * 256) * 8;
            int row = e >> 5, colk = e & 31;
            int gr = m0 + row;
            float va[8];
            if (gr < M) {
                float4 f0 = *(const float4*)&A[(size_t)gr * K + kc + colk];
                float4 f1 = *(const float4*)&A[(size_t)gr * K + kc + colk + 4];
                va[0] = f0.x; va[1] = f0.y; va[2] = f0.z; va[3] = f0.w;
                va[4] = f1.x; va[5] = f1.y; va[6] = f1.z; va[7] = f1.w;
            } else {
#pragma unroll
                for (int i = 0; i < 8; i++) va[i] = 0.f;
            }
            short8 vh, vl;
#pragma unroll
            for (int i = 0; i < 8; i++) {
                u16 h = f2bf(va[i]);
                vh[i] = (short)h;
                vl[i] = (short)f2bf(va[i] - bf2f(h));
            }
            *(short8*)&sAh[row * LDA + colk] = vh;
            *(short8*)&sAl[row * LDA + colk] = vl;
        }
        // stage B^T: 128x32 hi/lo bf16 copies (16 elems/thread/version)
#pragma unroll
        for (int j = 0; j < 2; j++) {
            int e = (tid + j * 256) * 8;
            int nn = e >> 5, colk = e & 31;
            int gn = n0 + nn;
            uint4 vh = zero4, vl = zero4;
            if (gn < Ntot) {
                vh = *(const uint4*)&BThi[(size_t)gn * K + kc + colk];
                vl = *(const uint4*)&BTlo[(size_t)gn * K + kc + colk];
            }
            *(uint4*)&sBh[nn * LDA + colk] = vh;
            *(uint4*)&sBl[nn * LDA + colk] = vl;
        }
        __syncthreads();

        short8 ah[2], al[2];
#pragma unroll
        for (int mi = 0; mi < 2; mi++) {
            int row = wave * 32 + mi * 16 + fm;
            ah[mi] = *(const short8*)&sAh[row * LDA + q * 8];
            al[mi] = *(const short8*)&sAl[row * LDA + q * 8];
        }
#pragma unroll
        for (int ni = 0; ni < 8; ni++) {
            int nn = ni * 16 + fm;
            short8 bh = *(const short8*)&sBh[nn * LDA + q * 8];
            short8 bl = *(const short8*)&sBl[nn * LDA + q * 8];
#pragma unroll
            for (int mi = 0; mi < 2; mi++) {
                acc[mi][ni] = __builtin_amdgcn_mfma_f32_16x16x32_bf16(ah[mi], bh, acc[mi][ni], 0, 0, 0);
                acc[mi][ni] = __builtin_amdgcn_mfma_f32_16x16x32_bf16(ah[mi], bl, acc[mi][ni], 0, 0, 0);
                acc[mi][ni] = __builtin_amdgcn_mfma_f32_16x16x32_bf16(al[mi], bh, acc[mi][ni], 0, 0, 0);
            }
        }
        __syncthreads();
    }

    // epilogue: frag C[row=(q*4+r), col=fm]
#pragma unroll
    for (int mi = 0; mi < 2; mi++) {
#pragma unroll
        for (int ni = 0; ni < 8; ni++) {
            int colg = n0 + ni * 16 + fm;
            if (colg >= Ntot) continue;
#pragma unroll
            for (int r = 0; r < 4; r++) {
                int rowg = m0 + wave * 32 + mi * 16 + q * 4 + r;
                if (rowg >= M) continue;
                float v = acc[mi][ni][r];
                if (colg < Nb) {
                    Cb[(size_t)rowg * strideB + colg] = f2bf(v);
                } else {
                    int cf = colg - Nb;
                    Cf[(size_t)rowg * strideF + cf] = v + biasf[cf];
                }
            }
        }
    }
}

// ---------------- per-node attention coefficients (bf16 xh) ----------------
__global__ __launch_bounds__(256) void alpha_kernel(const u16* __restrict__ xh,
                                                    const float* __restrict__ a_s,
                                                    const float* __restrict__ a_d,
                                                    float* __restrict__ as_o,
                                                    float* __restrict__ ad_o, int C) {
    int n = blockIdx.x;
    int w = threadIdx.x >> 6, lane = threadIdx.x & 63;
    const u16* row = xh + (size_t)n * 4 * C + (size_t)w * C;
    float ss = 0.f, sd = 0.f;
    for (int c = lane; c < C; c += 64) {
        float v = bf2f(row[c]);
        ss += v * a_s[w * C + c];
        sd += v * a_d[w * C + c];
    }
    for (int o = 32; o; o >>= 1) {
        ss += __shfl_xor(ss, o, 64);
        sd += __shfl_xor(sd, o, 64);
    }
    if (!lane) {
        as_o[n * 4 + w] = ss;
        ad_o[n * 4 + w] = sd;
    }
}

// ---------------- per-(node,head) online-softmax stats ----------------
__global__ __launch_bounds__(256) void stats_kernel(const int* __restrict__ rowp,
                                                    const int* __restrict__ col,
                                                    const float* __restrict__ asrc,
                                                    const float* __restrict__ adst,
                                                    float* __restrict__ m_o,
                                                    float* __restrict__ rd_o, int N) {
    int i = blockIdx.x * 256 + threadIdx.x;
    if (i >= N * 4) return;
    int n = i >> 2, h = i & 3;
    int r0 = rowp[n], r1 = rowp[n + 1];
    float ad = adst[i];
    float m = -3.4e38f, s = 0.f;
    for (int e = r0; e < r1; e++) {
        int sc = col[e];
        float l = lrelu(asrc[sc * 4 + h] + ad);
        float nm = fmaxf(m, l);
        s = s * __expf(m - nm) + __expf(l - nm);
        m = nm;
    }
    m_o[i] = m;
    rd_o[i] = 1.f / (s + 1e-16f);
}

// ---------------- per-edge alpha ----------------
__global__ __launch_bounds__(256) void edge_alpha_kernel(const int* __restrict__ col,
                                                         const int* __restrict__ dstE,
                                                         const float* __restrict__ asrc,
                                                         const float* __restrict__ adst,
                                                         const float* __restrict__ m_,
                                                         const float* __restrict__ rd_,
                                                         float* __restrict__ alphaE, int E) {
    int i = blockIdx.x * 256 + threadIdx.x;
    if (i >= E * 4) return;
    int e = i >> 2, h = i & 3;
    int sc = col[e], d = dstE[e];
    float l = lrelu(asrc[sc * 4 + h] + adst[d * 4 + h]);
    alphaE[i] = __expf(l - m_[d * 4 + h]) * rd_[d * 4 + h];
}

// ---------------- gather+FMA aggregate, HC=256 (layers 1/2) ----------------
// res/out may alias (in-place residual).
__global__ __launch_bounds__(256) void agg_kernel_256(const u16* __restrict__ xh,
                                                      const int* __restrict__ rowp,
                                                      const int* __restrict__ col,
                                                      const float* __restrict__ alphaE,
                                                      const float* __restrict__ bias,
                                                      const float* res,
                                                      float* out) {
    int n = blockIdx.x, tid = threadIdx.x;
    int r0 = rowp[n], deg = rowp[n + 1] - r0;
    __shared__ int s_src[64];
    __shared__ float s_al[64][4];
    __shared__ float s_part[2][HC12];
    int g = tid >> 7;
    int sub = tid & 127;
    int c = sub * 2;
    int h = sub >> 5;
    float a0 = 0.f, a1 = 0.f;
    for (int kb = 0; kb < deg; kb += 64) {
        int cn = min(64, deg - kb);
        __syncthreads();
        if (tid < cn) s_src[tid] = col[r0 + kb + tid];
        for (int idx = tid; idx < cn * 4; idx += 256)
            s_al[idx >> 2][idx & 3] = alphaE[(size_t)(r0 + kb) * 4 + idx];
        __syncthreads();
#pragma unroll 4
        for (int kk = g; kk < cn; kk += 2) {
            u32 v = *(const u32*)&xh[(size_t)s_src[kk] * HC12 + c];
            float al = s_al[kk][h];
            a0 += al * bf2f((u16)(v & 0xffff));
            a1 += al * bf2f((u16)(v >> 16));
        }
    }
    s_part[g][c] = a0;
    s_part[g][c + 1] = a1;
    __syncthreads();
    float v = s_part[0][tid] + s_part[1][tid] + bias[tid] + res[(size_t)n * HC12 + tid];
    out[(size_t)n * HC12 + tid] = v > 0.f ? v : expm1f(v);
}

// ---------------- layer 3 gather: HC=484, mean heads + b3 + lin3 -> d_out ----------------
__global__ __launch_bounds__(256) void agg_out_kernel(const u16* __restrict__ xh,
                                                      const int* __restrict__ rowp,
                                                      const int* __restrict__ col,
                                                      const float* __restrict__ alphaE,
                                                      const float* __restrict__ b3,
                                                      const float* __restrict__ lin3,
                                                      float* __restrict__ out) {
    int n = blockIdx.x, tid = threadIdx.x;
    int r0 = rowp[n], deg = rowp[n + 1] - r0;
    __shared__ int s_src[64];
    __shared__ float s_al[64][4];
    __shared__ float s_out[HC3];
    bool act = tid < 242;
    int c0 = 2 * tid, c1 = c0 + 1;
    int h0 = c0 >= 363 ? 3 : (c0 >= 242 ? 2 : (c0 >= 121 ? 1 : 0));
    int h1 = c1 >= 363 ? 3 : (c1 >= 242 ? 2 : (c1 >= 121 ? 1 : 0));
    float a0 = 0.f, a1 = 0.f;
    for (int kb = 0; kb < deg; kb += 64) {
        int cn = min(64, deg - kb);
        __syncthreads();
        if (tid < cn) s_src[tid] = col[r0 + kb + tid];
        for (int idx = tid; idx < cn * 4; idx += 256)
            s_al[idx >> 2][idx & 3] = alphaE[(size_t)(r0 + kb) * 4 + idx];
        __syncthreads();
        if (act) {
#pragma unroll 4
            for (int kk = 0; kk < cn; kk++) {
                u32 v = *(const u32*)&xh[(size_t)s_src[kk] * HC3 + c0];
                a0 += s_al[kk][h0] * bf2f((u16)(v & 0xffff));
                a1 += s_al[kk][h1] * bf2f((u16)(v >> 16));
            }
        }
    }
    if (act) { s_out[c0] = a0; s_out[c1] = a1; }
    __syncthreads();
    if (tid < NCLS) {
        float o = 0.25f * (s_out[tid] + s_out[NCLS + tid] + s_out[2 * NCLS + tid] + s_out[3 * NCLS + tid])
                  + b3[tid] + lin3[(size_t)n * NCLS + tid];
        out[(size_t)n * NCLS + tid] = o;
    }
}

extern "C" void kernel_launch(void* const* d_in, const int* in_sizes, int n_in,
                              void* d_out, int out_size, void* d_ws, size_t ws_size,
                              hipStream_t stream) {
    const float* x   = (const float*)d_in[0];
    const int*   ei  = (const int*)d_in[1];
    const float* W1  = (const float*)d_in[2];
    const float* a1s = (const float*)d_in[3];
    const float* a1d = (const float*)d_in[4];
    const float* b1  = (const float*)d_in[5];
    const float* l1W = (const float*)d_in[6];
    const float* l1b = (const float*)d_in[7];
    const float* W2  = (const float*)d_in[8];
    const float* a2s = (const float*)d_in[9];
    const float* a2d = (const float*)d_in[10];
    const float* b2  = (const float*)d_in[11];
    const float* W3  = (const float*)d_in[12];
    const float* a3s = (const float*)d_in[13];
    const float* a3d = (const float*)d_in[14];
    const float* b3  = (const float*)d_in[15];
    const float* l3W = (const float*)d_in[16];
    const float* l3b = (const float*)d_in[17];

    const int N = in_sizes[0] / F_IN;   // 50000
    const int E = in_sizes[1] / 2;      // 400000
    const int* srcv = ei;
    const int* dstv = ei + E;

    char* ws = (char*)d_ws;
    size_t off = 0;
    auto alloc = [&](size_t bytes) -> char* {
        char* p = ws + off;
        off += (bytes + 255) & ~(size_t)255;
        return p;
    };
    u16*   xh   = (u16*)alloc((size_t)N * HC3 * 2);
    float* h1   = (float*)alloc((size_t)N * HC12 * 4);
    float* h2   = (float*)alloc((size_t)N * HC12 * 4);
    float* lin  = (float*)alloc((size_t)N * NCLS * 4);
    float* as_  = (float*)alloc((size_t)N * 4 * 4);
    float* ad_  = (float*)alloc((size_t)N * 4 * 4);
    float* m_   = (float*)alloc((size_t)N * 4 * 4);
    float* rd_  = (float*)alloc((size_t)N * 4 * 4);
    int* rowp   = (int*)alloc((size_t)(N + 1) * 4);
    int* degc   = (int*)alloc((size_t)N * 4);
    int* cur    = (int*)alloc((size_t)N * 4);
    int* col    = (int*)alloc((size_t)E * 4);
    int* dstE   = (int*)alloc((size_t)E * 4);
    float* alphaE = (float*)alloc((size_t)E * 4 * 4);
    // combined transposed-split weights
    u16* C1h = (u16*)alloc((size_t)512 * 128 * 2);   // [W1 ; l1W] -> [512][128]
    u16* C1l = (u16*)alloc((size_t)512 * 128 * 2);
    u16* C2h = (u16*)alloc((size_t)256 * 256 * 2);   // W2 -> [256][256]
    u16* C2l = (u16*)alloc((size_t)256 * 256 * 2);
    u16* C3h = (u16*)alloc((size_t)605 * 256 * 2);   // [W3 ; l3W] -> [605][256]
    u16* C3l = (u16*)alloc((size_t)605 * 256 * 2);
    (void)ws_size; (void)n_in; (void)out_size;

    // ---- CSR build ----
    hipMemsetAsync(degc, 0, (size_t)N * 4, stream);
    hipMemsetAsync(cur, 0, (size_t)N * 4, stream);
    hist_kernel<<<(E + 255) / 256, 256, 0, stream>>>(dstv, degc, E);
    scan_kernel<<<1, 1024, 0, stream>>>(degc, rowp, N);
    scatter_kernel<<<(E + 255) / 256, 256, 0, stream>>>(srcv, dstv, rowp, cur, col, dstE, E);

    // ---- fused weight splits ----
    splitT_all_kernel<<<(285952 + 255) / 256, 256, 0, stream>>>(W1, l1W, W2, W3, l3W,
                                                                C1h, C1l, C2h, C2l, C3h, C3l);

    int mgrid = (N + BM - 1) / BM;
    int sgrid = (N * 4 + 255) / 256;
    int egrid = (E * 4 + 255) / 256;

    // ---- layer 1: one GEMM, N=512 (cols 0-255 -> xh bf16, 256-511 -> h1 fp32 + l1b) ----
    gemm_mfma_split<<<dim3(4, mgrid), 256, 0, stream>>>(x, C1h, C1l, N, F_IN, 512,
                                                        256, xh, 256, h1, l1b, 256);
    alpha_kernel<<<N, 256, 0, stream>>>(xh, a1s, a1d, as_, ad_, 64);
    stats_kernel<<<sgrid, 256, 0, stream>>>(rowp, col, as_, ad_, m_, rd_, N);
    edge_alpha_kernel<<<egrid, 256, 0, stream>>>(col, dstE, as_, ad_, m_, rd_, alphaE, E);
    agg_kernel_256<<<N, 256, 0, stream>>>(xh, rowp, col, alphaE, b1, h1, h1);  // in-place residual

    // ---- layer 2: N=256, all bf16 ----
    gemm_mfma_split<<<dim3(2, mgrid), 256, 0, stream>>>(h1, C2h, C2l, N, HC12, 256,
                                                        256, xh, 256, nullptr, nullptr, 0);
    alpha_kernel<<<N, 256, 0, stream>>>(xh, a2s, a2d, as_, ad_, 64);
    stats_kernel<<<sgrid, 256, 0, stream>>>(rowp, col, as_, ad_, m_, rd_, N);
    edge_alpha_kernel<<<egrid, 256, 0, stream>>>(col, dstE, as_, ad_, m_, rd_, alphaE, E);
    agg_kernel_256<<<N, 256, 0, stream>>>(xh, rowp, col, alphaE, b2, h1, h2);

    // ---- layer 3: one GEMM, N=605 (cols 0-483 -> xh bf16, 484-604 -> lin fp32 + l3b) ----
    gemm_mfma_split<<<dim3(5, mgrid), 256, 0, stream>>>(h2, C3h, C3l, N, HC12, 605,
                                                        484, xh, 484, lin, l3b, NCLS);
    alpha_kernel<<<N, 256, 0, stream>>>(xh, a3s, a3d, as_, ad_, NCLS);
    stats_kernel<<<sgrid, 256, 0, stream>>>(rowp, col, as_, ad_, m_, rd_, N);
    edge_alpha_kernel<<<egrid, 256, 0, stream>>>(col, dstE, as_, ad_, m_, rd_, alphaE, E);
    agg_out_kernel<<<N, 256, 0, stream>>>(xh, rowp, col, alphaE, b3, lin, (float*)d_out);
}

// Round 7
// 734.984 us; speedup vs baseline: 1.9983x; 1.0340x over previous
//
#include <hip/hip_runtime.h>
#include <hip/hip_bf16.h>
#include <cstdint>
#include <cstddef>

#define F_IN 128
#define HC12 256   // HEADS*HID for layers 1/2
#define HC3 484    // OUT_HEADS*N_CLS for layer 3
#define NCLS 121

typedef unsigned short u16;
typedef unsigned int u32;
typedef __attribute__((ext_vector_type(8))) short short8;
typedef __attribute__((ext_vector_type(4))) float float4v;

static __device__ __forceinline__ float lrelu(float x) { return x > 0.f ? x : 0.2f * x; }

static __device__ __forceinline__ u16 f2bf(float f) {
    union { float f; unsigned u; } v; v.f = f;
    unsigned r = v.u + 0x7FFF + ((v.u >> 16) & 1);
    return (u16)(r >> 16);
}
static __device__ __forceinline__ float bf2f(u16 h) {
    union { unsigned u; float f; } v; v.u = ((unsigned)h) << 16;
    return v.f;
}
// packed fp32x2 -> bf16x2 (v_cvt_pk_bf16_f32 on gfx950)
static __device__ __forceinline__ u32 pk_bf16(float a, float b) {
    float2 f; f.x = a; f.y = b;
    union { __hip_bfloat162 b2; u32 u; } cv;
    cv.b2 = __float22bfloat162_rn(f);
    return cv.u;
}

// ---------------- CSR build ----------------
__global__ void hist_kernel(const int* __restrict__ dst, int* __restrict__ deg, int E) {
    int e = blockIdx.x * 256 + threadIdx.x;
    if (e < E) atomicAdd(&deg[dst[e]], 1);
}

// 4 elems/thread, 13 outer iterations
__global__ __launch_bounds__(1024) void scan_kernel(const int* __restrict__ deg,
                                                    int* __restrict__ rowp, int N) {
    __shared__ int swave[16];
    __shared__ int s_carry;
    int tid = threadIdx.x;
    int w = tid >> 6, lane = tid & 63;
    if (tid == 0) { rowp[0] = 0; s_carry = 0; }
    __syncthreads();
    for (int base = 0; base < N; base += 4096) {
        int i0 = base + tid * 4;
        int v0 = (i0     < N) ? deg[i0]     : 0;
        int v1 = (i0 + 1 < N) ? deg[i0 + 1] : 0;
        int v2 = (i0 + 2 < N) ? deg[i0 + 2] : 0;
        int v3 = (i0 + 3 < N) ? deg[i0 + 3] : 0;
        int t = v0 + v1 + v2 + v3;
        int sc = t;
#pragma unroll
        for (int off = 1; off < 64; off <<= 1) {
            int u = __shfl_up(sc, off, 64);
            if (lane >= off) sc += u;
        }
        if (lane == 63) swave[w] = sc;
        __syncthreads();
        if (w == 0) {
            int ws = (lane < 16) ? swave[lane] : 0;
#pragma unroll
            for (int off = 1; off < 16; off <<= 1) {
                int u = __shfl_up(ws, off, 64);
                if (lane >= off) ws += u;
            }
            if (lane < 16) swave[lane] = ws;
        }
        __syncthreads();
        int carry = s_carry;
        int tb = carry + ((w > 0) ? swave[w - 1] : 0) + sc - t;  // exclusive base for thread
        if (i0     < N) rowp[i0 + 1] = tb + v0;
        if (i0 + 1 < N) rowp[i0 + 2] = tb + v0 + v1;
        if (i0 + 2 < N) rowp[i0 + 3] = tb + v0 + v1 + v2;
        if (i0 + 3 < N) rowp[i0 + 4] = tb + t;
        __syncthreads();
        if (tid == 1023) s_carry = carry + swave[15];
        __syncthreads();
    }
}

__global__ void scatter_kernel(const int* __restrict__ src, const int* __restrict__ dst,
                               const int* __restrict__ rowp, int* __restrict__ cur,
                               int* __restrict__ col, int E) {
    int e = blockIdx.x * 256 + threadIdx.x;
    if (e < E) {
        int d = dst[e];
        int pos = rowp[d] + atomicAdd(&cur[d], 1);
        col[pos] = src[e];
    }
}

// ---------------- fused weight split+transpose (all 5 matrices, 1 launch) ----------------
__global__ void splitT_all_kernel(const float* W1, const float* l1W, const float* W2,
                                  const float* W3, const float* l3W,
                                  u16* C1h, u16* C1l, u16* C2h, u16* C2l,
                                  u16* C3h, u16* C3l) {
    int i = blockIdx.x * 256 + threadIdx.x;
    const float* B; u16* hi; u16* lo; int K, N;
    if (i < 32768)       { B = W1;  hi = C1h;             lo = C1l;             K = 128; N = 256; }
    else if (i < 65536)  { B = l1W; hi = C1h + 256 * 128; lo = C1l + 256 * 128; K = 128; N = 256; i -= 32768; }
    else if (i < 131072) { B = W2;  hi = C2h;             lo = C2l;             K = 256; N = 256; i -= 65536; }
    else if (i < 254976) { B = W3;  hi = C3h;             lo = C3l;             K = 256; N = 484; i -= 131072; }
    else if (i < 285952) { B = l3W; hi = C3h + 484 * 256; lo = C3l + 484 * 256; K = 256; N = 121; i -= 254976; }
    else return;
    int n = i % N, k = i / N;
    float v = B[(size_t)k * N + n];
    u16 h = f2bf(v);
    hi[(size_t)n * K + k] = h;
    lo[(size_t)n * K + k] = f2bf(v - bf2f(h));
}

// ---------------- split-bf16 MFMA GEMM, 128x128 tile, 2x2 wave tiling, reg prefetch ----
// A: fp32 [M][K] (hi/lo split in-register, packed cvt). BT: bf16 hi/lo [Ntot][K].
// cols [0,Nb) -> bf16 Cb (strideB); cols [Nb,Ntot) -> fp32 Cf + biasf (strideF).
#define BM 128
#define BN 128
#define BK 32
#define LDA 40

__global__ __launch_bounds__(256, 2) void gemm_mfma_split(const float* __restrict__ A,
                                                          const u16* __restrict__ BThi,
                                                          const u16* __restrict__ BTlo,
                                                          int M, int K, int Ntot,
                                                          int Nb, u16* __restrict__ Cb, int strideB,
                                                          float* __restrict__ Cf,
                                                          const float* __restrict__ biasf, int strideF) {
    __shared__ __align__(16) u16 sAh[BM * LDA];
    __shared__ __align__(16) u16 sAl[BM * LDA];
    __shared__ __align__(16) u16 sBh[BN * LDA];
    __shared__ __align__(16) u16 sBl[BN * LDA];
    int tid = threadIdx.x;
    int wave = tid >> 6, lane = tid & 63;
    int wr = wave >> 1, wc = wave & 1;
    int m0 = blockIdx.y * BM, n0 = blockIdx.x * BN;
    int fm = lane & 15;
    int q = lane >> 4;

    int r0 = tid >> 2;        // staging row 0..63 (and +64 for group 1)
    int c0 = (tid & 3) * 8;   // staging col {0,8,16,24}

    float4v acc[4][4];
#pragma unroll
    for (int i = 0; i < 4; i++)
#pragma unroll
        for (int j = 0; j < 4; j++) acc[i][j] = (float4v){0.f, 0.f, 0.f, 0.f};

    const uint4 zero4 = {0u, 0u, 0u, 0u};
    const float4 zf4 = {0.f, 0.f, 0.f, 0.f};

    float4 pa[2][2];
    uint4 pbh[2], pbl[2];

    // prefetch chunk 0
#pragma unroll
    for (int j = 0; j < 2; j++) {
        int gr = m0 + r0 + j * 64;
        if (gr < M) {
            pa[j][0] = *(const float4*)&A[(size_t)gr * K + c0];
            pa[j][1] = *(const float4*)&A[(size_t)gr * K + c0 + 4];
        } else { pa[j][0] = zf4; pa[j][1] = zf4; }
        int gn = n0 + r0 + j * 64;
        if (gn < Ntot) {
            pbh[j] = *(const uint4*)&BThi[(size_t)gn * K + c0];
            pbl[j] = *(const uint4*)&BTlo[(size_t)gn * K + c0];
        } else { pbh[j] = zero4; pbl[j] = zero4; }
    }

    for (int kc = 0; kc < K; kc += BK) {
        // stage from prefetch regs (packed cvt for hi/lo split)
#pragma unroll
        for (int j = 0; j < 2; j++) {
            float va[8];
            va[0] = pa[j][0].x; va[1] = pa[j][0].y; va[2] = pa[j][0].z; va[3] = pa[j][0].w;
            va[4] = pa[j][1].x; va[5] = pa[j][1].y; va[6] = pa[j][1].z; va[7] = pa[j][1].w;
            uint4 vh, vl;
#pragma unroll
            for (int t = 0; t < 4; t++) {
                u32 hu = pk_bf16(va[2 * t], va[2 * t + 1]);
                float l0 = va[2 * t]     - bf2f((u16)(hu & 0xffff));
                float l1 = va[2 * t + 1] - bf2f((u16)(hu >> 16));
                ((u32*)&vh)[t] = hu;
                ((u32*)&vl)[t] = pk_bf16(l0, l1);
            }
            int row = r0 + j * 64;
            *(uint4*)&sAh[row * LDA + c0] = vh;
            *(uint4*)&sAl[row * LDA + c0] = vl;
            *(uint4*)&sBh[row * LDA + c0] = pbh[j];
            *(uint4*)&sBl[row * LDA + c0] = pbl[j];
        }
        __syncthreads();

        // issue prefetch for next chunk (flies during compute)
        int kn = kc + BK;
        if (kn < K) {
#pragma unroll
            for (int j = 0; j < 2; j++) {
                int gr = m0 + r0 + j * 64;
                if (gr < M) {
                    pa[j][0] = *(const float4*)&A[(size_t)gr * K + kn + c0];
                    pa[j][1] = *(const float4*)&A[(size_t)gr * K + kn + c0 + 4];
                } else { pa[j][0] = zf4; pa[j][1] = zf4; }
                int gn = n0 + r0 + j * 64;
                if (gn < Ntot) {
                    pbh[j] = *(const uint4*)&BThi[(size_t)gn * K + kn + c0];
                    pbl[j] = *(const uint4*)&BTlo[(size_t)gn * K + kn + c0];
                } else { pbh[j] = zero4; pbl[j] = zero4; }
            }
        }

        // compute: 4x4 frags per wave
        short8 ah[4], al[4];
#pragma unroll
        for (int mi = 0; mi < 4; mi++) {
            int row = wr * 64 + mi * 16 + fm;
            ah[mi] = *(const short8*)&sAh[row * LDA + q * 8];
            al[mi] = *(const short8*)&sAl[row * LDA + q * 8];
        }
#pragma unroll
        for (int ni = 0; ni < 4; ni++) {
            int nn = wc * 64 + ni * 16 + fm;
            short8 bh = *(const short8*)&sBh[nn * LDA + q * 8];
            short8 bl = *(const short8*)&sBl[nn * LDA + q * 8];
#pragma unroll
            for (int mi = 0; mi < 4; mi++) {
                acc[mi][ni] = __builtin_amdgcn_mfma_f32_16x16x32_bf16(ah[mi], bh, acc[mi][ni], 0, 0, 0);
                acc[mi][ni] = __builtin_amdgcn_mfma_f32_16x16x32_bf16(ah[mi], bl, acc[mi][ni], 0, 0, 0);
                acc[mi][ni] = __builtin_amdgcn_mfma_f32_16x16x32_bf16(al[mi], bh, acc[mi][ni], 0, 0, 0);
            }
        }
        __syncthreads();
    }

    // epilogue: frag C[row=(q*4+r), col=fm]
#pragma unroll
    for (int mi = 0; mi < 4; mi++) {
#pragma unroll
        for (int ni = 0; ni < 4; ni++) {
            int colg = n0 + wc * 64 + ni * 16 + fm;
            if (colg >= Ntot) continue;
#pragma unroll
            for (int r = 0; r < 4; r++) {
                int rowg = m0 + wr * 64 + mi * 16 + q * 4 + r;
                if (rowg >= M) continue;
                float v = acc[mi][ni][r];
                if (colg < Nb) {
                    Cb[(size_t)rowg * strideB + colg] = f2bf(v);
                } else {
                    int cf = colg - Nb;
                    Cf[(size_t)rowg * strideF + cf] = v + biasf[cf];
                }
            }
        }
    }
}

// ---------------- per-node attention coefficients (bf16 xh) ----------------
__global__ __launch_bounds__(256) void alpha_kernel(const u16* __restrict__ xh,
                                                    const float* __restrict__ a_s,
                                                    const float* __restrict__ a_d,
                                                    float* __restrict__ as_o,
                                                    float* __restrict__ ad_o, int C) {
    int n = blockIdx.x;
    int w = threadIdx.x >> 6, lane = threadIdx.x & 63;
    const u16* row = xh + (size_t)n * 4 * C + (size_t)w * C;
    float ss = 0.f, sd = 0.f;
    for (int c = lane; c < C; c += 64) {
        float v = bf2f(row[c]);
        ss += v * a_s[w * C + c];
        sd += v * a_d[w * C + c];
    }
    for (int o = 32; o; o >>= 1) {
        ss += __shfl_xor(ss, o, 64);
        sd += __shfl_xor(sd, o, 64);
    }
    if (!lane) {
        as_o[n * 4 + w] = ss;
        ad_o[n * 4 + w] = sd;
    }
}

// ---------------- fused per-(node,head) softmax stats + per-edge alpha ----------------
__global__ __launch_bounds__(256) void stats_alpha_kernel(const int* __restrict__ rowp,
                                                          const int* __restrict__ col,
                                                          const float* __restrict__ asrc,
                                                          const float* __restrict__ adst,
                                                          float* __restrict__ alphaE, int N) {
    int i = blockIdx.x * 256 + threadIdx.x;
    if (i >= N * 4) return;
    int n = i >> 2, h = i & 3;
    int r0 = rowp[n], r1 = rowp[n + 1];
    float ad = adst[i];
    float m = -3.4e38f, s = 0.f;
    for (int e = r0; e < r1; e++) {
        int sc = col[e];
        float l = lrelu(asrc[sc * 4 + h] + ad);
        float nm = fmaxf(m, l);
        s = s * __expf(m - nm) + __expf(l - nm);
        m = nm;
    }
    float rd = 1.f / (s + 1e-16f);
    for (int e = r0; e < r1; e++) {
        int sc = col[e];
        float l = lrelu(asrc[sc * 4 + h] + ad);
        alphaE[(size_t)e * 4 + h] = __expf(l - m) * rd;
    }
}

// ---------------- gather+FMA aggregate, HC=256 (layers 1/2) ----------------
// res/out may alias (in-place residual).
__global__ __launch_bounds__(256) void agg_kernel_256(const u16* __restrict__ xh,
                                                      const int* __restrict__ rowp,
                                                      const int* __restrict__ col,
                                                      const float* __restrict__ alphaE,
                                                      const float* __restrict__ bias,
                                                      const float* res,
                                                      float* out) {
    int n = blockIdx.x, tid = threadIdx.x;
    int r0 = rowp[n], deg = rowp[n + 1] - r0;
    __shared__ int s_src[64];
    __shared__ float s_al[64][4];
    __shared__ float s_part[2][HC12];
    int g = tid >> 7;
    int sub = tid & 127;
    int c = sub * 2;
    int h = sub >> 5;
    float a0 = 0.f, a1 = 0.f;
    for (int kb = 0; kb < deg; kb += 64) {
        int cn = min(64, deg - kb);
        __syncthreads();
        if (tid < cn) s_src[tid] = col[r0 + kb + tid];
        for (int idx = tid; idx < cn * 4; idx += 256)
            s_al[idx >> 2][idx & 3] = alphaE[(size_t)(r0 + kb) * 4 + idx];
        __syncthreads();
#pragma unroll 4
        for (int kk = g; kk < cn; kk += 2) {
            u32 v = *(const u32*)&xh[(size_t)s_src[kk] * HC12 + c];
            float al = s_al[kk][h];
            a0 += al * bf2f((u16)(v & 0xffff));
            a1 += al * bf2f((u16)(v >> 16));
        }
    }
    s_part[g][c] = a0;
    s_part[g][c + 1] = a1;
    __syncthreads();
    float v = s_part[0][tid] + s_part[1][tid] + bias[tid] + res[(size_t)n * HC12 + tid];
    out[(size_t)n * HC12 + tid] = v > 0.f ? v : expm1f(v);
}

// ---------------- layer 3 gather: HC=484, mean heads + b3 + lin3 -> d_out ----------------
__global__ __launch_bounds__(256) void agg_out_kernel(const u16* __restrict__ xh,
                                                      const int* __restrict__ rowp,
                                                      const int* __restrict__ col,
                                                      const float* __restrict__ alphaE,
                                                      const float* __restrict__ b3,
                                                      const float* __restrict__ lin3,
                                                      float* __restrict__ out) {
    int n = blockIdx.x, tid = threadIdx.x;
    int r0 = rowp[n], deg = rowp[n + 1] - r0;
    __shared__ int s_src[64];
    __shared__ float s_al[64][4];
    __shared__ float s_out[HC3];
    bool act = tid < 242;
    int c0 = 2 * tid, c1 = c0 + 1;
    int h0 = c0 >= 363 ? 3 : (c0 >= 242 ? 2 : (c0 >= 121 ? 1 : 0));
    int h1 = c1 >= 363 ? 3 : (c1 >= 242 ? 2 : (c1 >= 121 ? 1 : 0));
    float a0 = 0.f, a1 = 0.f;
    for (int kb = 0; kb < deg; kb += 64) {
        int cn = min(64, deg - kb);
        __syncthreads();
        if (tid < cn) s_src[tid] = col[r0 + kb + tid];
        for (int idx = tid; idx < cn * 4; idx += 256)
            s_al[idx >> 2][idx & 3] = alphaE[(size_t)(r0 + kb) * 4 + idx];
        __syncthreads();
        if (act) {
#pragma unroll 4
            for (int kk = 0; kk < cn; kk++) {
                u32 v = *(const u32*)&xh[(size_t)s_src[kk] * HC3 + c0];
                a0 += s_al[kk][h0] * bf2f((u16)(v & 0xffff));
                a1 += s_al[kk][h1] * bf2f((u16)(v >> 16));
            }
        }
    }
    if (act) { s_out[c0] = a0; s_out[c1] = a1; }
    __syncthreads();
    if (tid < NCLS) {
        float o = 0.25f * (s_out[tid] + s_out[NCLS + tid] + s_out[2 * NCLS + tid] + s_out[3 * NCLS + tid])
                  + b3[tid] + lin3[(size_t)n * NCLS + tid];
        out[(size_t)n * NCLS + tid] = o;
    }
}

extern "C" void kernel_launch(void* const* d_in, const int* in_sizes, int n_in,
                              void* d_out, int out_size, void* d_ws, size_t ws_size,
                              hipStream_t stream) {
    const float* x   = (const float*)d_in[0];
    const int*   ei  = (const int*)d_in[1];
    const float* W1  = (const float*)d_in[2];
    const float* a1s = (const float*)d_in[3];
    const float* a1d = (const float*)d_in[4];
    const float* b1  = (const float*)d_in[5];
    const float* l1W = (const float*)d_in[6];
    const float* l1b = (const float*)d_in[7];
    const float* W2  = (const float*)d_in[8];
    const float* a2s = (const float*)d_in[9];
    const float* a2d = (const float*)d_in[10];
    const float* b2  = (const float*)d_in[11];
    const float* W3  = (const float*)d_in[12];
    const float* a3s = (const float*)d_in[13];
    const float* a3d = (const float*)d_in[14];
    const float* b3  = (const float*)d_in[15];
    const float* l3W = (const float*)d_in[16];
    const float* l3b = (const float*)d_in[17];

    const int N = in_sizes[0] / F_IN;   // 50000
    const int E = in_sizes[1] / 2;      // 400000
    const int* srcv = ei;
    const int* dstv = ei + E;

    char* ws = (char*)d_ws;
    size_t off = 0;
    auto alloc = [&](size_t bytes) -> char* {
        char* p = ws + off;
        off += (bytes + 255) & ~(size_t)255;
        return p;
    };
    u16*   xh   = (u16*)alloc((size_t)N * HC3 * 2);
    float* h1   = (float*)alloc((size_t)N * HC12 * 4);
    float* h2   = (float*)alloc((size_t)N * HC12 * 4);
    float* lin  = (float*)alloc((size_t)N * NCLS * 4);
    float* as_  = (float*)alloc((size_t)N * 4 * 4);
    float* ad_  = (float*)alloc((size_t)N * 4 * 4);
    int* rowp   = (int*)alloc((size_t)(N + 1) * 4);
    int* degc   = (int*)alloc((size_t)N * 4);
    int* cur    = (int*)alloc((size_t)N * 4);
    int* col    = (int*)alloc((size_t)E * 4);
    float* alphaE = (float*)alloc((size_t)E * 4 * 4);
    u16* C1h = (u16*)alloc((size_t)512 * 128 * 2);   // [W1 ; l1W] -> [512][128]
    u16* C1l = (u16*)alloc((size_t)512 * 128 * 2);
    u16* C2h = (u16*)alloc((size_t)256 * 256 * 2);   // W2 -> [256][256]
    u16* C2l = (u16*)alloc((size_t)256 * 256 * 2);
    u16* C3h = (u16*)alloc((size_t)605 * 256 * 2);   // [W3 ; l3W] -> [605][256]
    u16* C3l = (u16*)alloc((size_t)605 * 256 * 2);
    (void)ws_size; (void)n_in; (void)out_size;

    // ---- CSR build ----
    hipMemsetAsync(degc, 0, (size_t)N * 4, stream);
    hipMemsetAsync(cur, 0, (size_t)N * 4, stream);
    hist_kernel<<<(E + 255) / 256, 256, 0, stream>>>(dstv, degc, E);
    scan_kernel<<<1, 1024, 0, stream>>>(degc, rowp, N);
    scatter_kernel<<<(E + 255) / 256, 256, 0, stream>>>(srcv, dstv, rowp, cur, col, E);

    // ---- fused weight splits ----
    splitT_all_kernel<<<(285952 + 255) / 256, 256, 0, stream>>>(W1, l1W, W2, W3, l3W,
                                                                C1h, C1l, C2h, C2l, C3h, C3l);

    int mgrid = (N + BM - 1) / BM;
    int sgrid = (N * 4 + 255) / 256;

    // ---- layer 1: one GEMM, N=512 (cols 0-255 -> xh bf16, 256-511 -> h1 fp32 + l1b) ----
    gemm_mfma_split<<<dim3(4, mgrid), 256, 0, stream>>>(x, C1h, C1l, N, F_IN, 512,
                                                        256, xh, 256, h1, l1b, 256);
    alpha_kernel<<<N, 256, 0, stream>>>(xh, a1s, a1d, as_, ad_, 64);
    stats_alpha_kernel<<<sgrid, 256, 0, stream>>>(rowp, col, as_, ad_, alphaE, N);
    agg_kernel_256<<<N, 256, 0, stream>>>(xh, rowp, col, alphaE, b1, h1, h1);  // in-place residual

    // ---- layer 2: N=256, all bf16 ----
    gemm_mfma_split<<<dim3(2, mgrid), 256, 0, stream>>>(h1, C2h, C2l, N, HC12, 256,
                                                        256, xh, 256, nullptr, nullptr, 0);
    alpha_kernel<<<N, 256, 0, stream>>>(xh, a2s, a2d, as_, ad_, 64);
    stats_alpha_kernel<<<sgrid, 256, 0, stream>>>(rowp, col, as_, ad_, alphaE, N);
    agg_kernel_256<<<N, 256, 0, stream>>>(xh, rowp, col, alphaE, b2, h1, h2);

    // ---- layer 3: one GEMM, N=605 (cols 0-483 -> xh bf16, 484-604 -> lin fp32 + l3b) ----
    gemm_mfma_split<<<dim3(5, mgrid), 256, 0, stream>>>(h2, C3h, C3l, N, HC12, 605,
                                                        484, xh, 484, lin, l3b, NCLS);
    alpha_kernel<<<N, 256, 0, stream>>>(xh, a3s, a3d, as_, ad_, NCLS);
    stats_alpha_kernel<<<sgrid, 256, 0, stream>>>(rowp, col, as_, ad_, alphaE, N);
    agg_out_kernel<<<N, 256, 0, stream>>>(xh, rowp, col, alphaE, b3, lin, (float*)d_out);
}

// Round 8
// 722.412 us; speedup vs baseline: 2.0331x; 1.0174x over previous
//
#include <hip/hip_runtime.h>
#include <hip/hip_bf16.h>
#include <cstdint>
#include <cstddef>

#define F_IN 128
#define HC12 256   // HEADS*HID for layers 1/2
#define HC3 484    // OUT_HEADS*N_CLS for layer 3
#define NCLS 121

typedef unsigned short u16;
typedef unsigned int u32;
typedef __attribute__((ext_vector_type(8))) short short8;
typedef __attribute__((ext_vector_type(4))) float float4v;

static __device__ __forceinline__ float lrelu(float x) { return x > 0.f ? x : 0.2f * x; }

static __device__ __forceinline__ u16 f2bf(float f) {
    union { float f; unsigned u; } v; v.f = f;
    unsigned r = v.u + 0x7FFF + ((v.u >> 16) & 1);
    return (u16)(r >> 16);
}
static __device__ __forceinline__ float bf2f(u16 h) {
    union { unsigned u; float f; } v; v.u = ((unsigned)h) << 16;
    return v.f;
}
static __device__ __forceinline__ u32 pk_bf16(float a, float b) {
    float2 f; f.x = a; f.y = b;
    union { __hip_bfloat162 b2; u32 u; } cv;
    cv.b2 = __float22bfloat162_rn(f);
    return cv.u;
}

// ---------------- CSR build ----------------
__global__ void hist_kernel(const int* __restrict__ dst, int* __restrict__ deg, int E) {
    int e = blockIdx.x * 256 + threadIdx.x;
    if (e < E) atomicAdd(&deg[dst[e]], 1);
}

__global__ __launch_bounds__(1024) void scan_kernel(const int* __restrict__ deg,
                                                    int* __restrict__ rowp, int N) {
    __shared__ int swave[16];
    __shared__ int s_carry;
    int tid = threadIdx.x;
    int w = tid >> 6, lane = tid & 63;
    if (tid == 0) { rowp[0] = 0; s_carry = 0; }
    __syncthreads();
    for (int base = 0; base < N; base += 4096) {
        int i0 = base + tid * 4;
        int v0 = (i0     < N) ? deg[i0]     : 0;
        int v1 = (i0 + 1 < N) ? deg[i0 + 1] : 0;
        int v2 = (i0 + 2 < N) ? deg[i0 + 2] : 0;
        int v3 = (i0 + 3 < N) ? deg[i0 + 3] : 0;
        int t = v0 + v1 + v2 + v3;
        int sc = t;
#pragma unroll
        for (int off = 1; off < 64; off <<= 1) {
            int u = __shfl_up(sc, off, 64);
            if (lane >= off) sc += u;
        }
        if (lane == 63) swave[w] = sc;
        __syncthreads();
        if (w == 0) {
            int ws = (lane < 16) ? swave[lane] : 0;
#pragma unroll
            for (int off = 1; off < 16; off <<= 1) {
                int u = __shfl_up(ws, off, 64);
                if (lane >= off) ws += u;
            }
            if (lane < 16) swave[lane] = ws;
        }
        __syncthreads();
        int carry = s_carry;
        int tb = carry + ((w > 0) ? swave[w - 1] : 0) + sc - t;
        if (i0     < N) rowp[i0 + 1] = tb + v0;
        if (i0 + 1 < N) rowp[i0 + 2] = tb + v0 + v1;
        if (i0 + 2 < N) rowp[i0 + 3] = tb + v0 + v1 + v2;
        if (i0 + 3 < N) rowp[i0 + 4] = tb + t;
        __syncthreads();
        if (tid == 1023) s_carry = carry + swave[15];
        __syncthreads();
    }
}

__global__ void scatter_kernel(const int* __restrict__ src, const int* __restrict__ dst,
                               const int* __restrict__ rowp, int* __restrict__ cur,
                               int* __restrict__ col, int E) {
    int e = blockIdx.x * 256 + threadIdx.x;
    if (e < E) {
        int d = dst[e];
        int pos = rowp[d] + atomicAdd(&cur[d], 1);
        col[pos] = src[e];
    }
}

// ---------------- fused weight split+transpose ----------------
__global__ void splitT_all_kernel(const float* W1, const float* l1W, const float* W2,
                                  const float* W3, const float* l3W,
                                  u16* C1h, u16* C1l, u16* C2h, u16* C2l,
                                  u16* C3h, u16* C3l) {
    int i = blockIdx.x * 256 + threadIdx.x;
    const float* B; u16* hi; u16* lo; int K, N;
    if (i < 32768)       { B = W1;  hi = C1h;             lo = C1l;             K = 128; N = 256; }
    else if (i < 65536)  { B = l1W; hi = C1h + 256 * 128; lo = C1l + 256 * 128; K = 128; N = 256; i -= 32768; }
    else if (i < 131072) { B = W2;  hi = C2h;             lo = C2l;             K = 256; N = 256; i -= 65536; }
    else if (i < 254976) { B = W3;  hi = C3h;             lo = C3l;             K = 256; N = 484; i -= 131072; }
    else if (i < 285952) { B = l3W; hi = C3h + 484 * 256; lo = C3l + 484 * 256; K = 256; N = 121; i -= 254976; }
    else return;
    int n = i % N, k = i / N;
    float v = B[(size_t)k * N + n];
    u16 h = f2bf(v);
    hi[(size_t)n * K + k] = h;
    lo[(size_t)n * K + k] = f2bf(v - bf2f(h));
}

// ---------------- split-bf16 MFMA GEMM, 128x128 tile, XCD-aware swizzle ----------------
// 1D grid of nx*ny blocks. Swizzle: same row-tile's col-blocks land 8 apart
// (same XCD under round-robin) so A-tile is fetched into one L2 and reused.
#define BM 128
#define BN 128
#define BK 32
#define LDA 40

__global__ __launch_bounds__(256, 2) void gemm_mfma_split(const float* __restrict__ A,
                                                          const u16* __restrict__ BThi,
                                                          const u16* __restrict__ BTlo,
                                                          int M, int K, int Ntot,
                                                          int nx, int ny,
                                                          int Nb, u16* __restrict__ Cb, int strideB,
                                                          float* __restrict__ Cf,
                                                          const float* __restrict__ biasf, int strideF) {
    __shared__ __align__(16) u16 sAh[BM * LDA];
    __shared__ __align__(16) u16 sAl[BM * LDA];
    __shared__ __align__(16) u16 sBh[BN * LDA];
    __shared__ __align__(16) u16 sBl[BN * LDA];
    int tid = threadIdx.x;
    int wave = tid >> 6, lane = tid & 63;
    int wr = wave >> 1, wc = wave & 1;

    // XCD-aware block swizzle
    int bid = blockIdx.x;
    int G = nx * 8;
    int g = bid / G;
    int rem = ny - g * 8;
    int rb, cb;
    if (rem >= 8) {
        int r = bid - g * G;
        rb = g * 8 + (r & 7);
        cb = r >> 3;
    } else {
        int t = bid - g * G;
        rb = g * 8 + t % rem;
        cb = t / rem;
    }
    int m0 = rb * BM, n0 = cb * BN;

    int fm = lane & 15;
    int q = lane >> 4;
    int r0 = tid >> 2;
    int c0 = (tid & 3) * 8;

    float4v acc[4][4];
#pragma unroll
    for (int i = 0; i < 4; i++)
#pragma unroll
        for (int j = 0; j < 4; j++) acc[i][j] = (float4v){0.f, 0.f, 0.f, 0.f};

    const uint4 zero4 = {0u, 0u, 0u, 0u};
    const float4 zf4 = {0.f, 0.f, 0.f, 0.f};

    float4 pa[2][2];
    uint4 pbh[2], pbl[2];

#pragma unroll
    for (int j = 0; j < 2; j++) {
        int gr = m0 + r0 + j * 64;
        if (gr < M) {
            pa[j][0] = *(const float4*)&A[(size_t)gr * K + c0];
            pa[j][1] = *(const float4*)&A[(size_t)gr * K + c0 + 4];
        } else { pa[j][0] = zf4; pa[j][1] = zf4; }
        int gn = n0 + r0 + j * 64;
        if (gn < Ntot) {
            pbh[j] = *(const uint4*)&BThi[(size_t)gn * K + c0];
            pbl[j] = *(const uint4*)&BTlo[(size_t)gn * K + c0];
        } else { pbh[j] = zero4; pbl[j] = zero4; }
    }

    for (int kc = 0; kc < K; kc += BK) {
#pragma unroll
        for (int j = 0; j < 2; j++) {
            float va[8];
            va[0] = pa[j][0].x; va[1] = pa[j][0].y; va[2] = pa[j][0].z; va[3] = pa[j][0].w;
            va[4] = pa[j][1].x; va[5] = pa[j][1].y; va[6] = pa[j][1].z; va[7] = pa[j][1].w;
            uint4 vh, vl;
#pragma unroll
            for (int t = 0; t < 4; t++) {
                u32 hu = pk_bf16(va[2 * t], va[2 * t + 1]);
                float l0 = va[2 * t]     - bf2f((u16)(hu & 0xffff));
                float l1 = va[2 * t + 1] - bf2f((u16)(hu >> 16));
                ((u32*)&vh)[t] = hu;
                ((u32*)&vl)[t] = pk_bf16(l0, l1);
            }
            int row = r0 + j * 64;
            *(uint4*)&sAh[row * LDA + c0] = vh;
            *(uint4*)&sAl[row * LDA + c0] = vl;
            *(uint4*)&sBh[row * LDA + c0] = pbh[j];
            *(uint4*)&sBl[row * LDA + c0] = pbl[j];
        }
        __syncthreads();

        int kn = kc + BK;
        if (kn < K) {
#pragma unroll
            for (int j = 0; j < 2; j++) {
                int gr = m0 + r0 + j * 64;
                if (gr < M) {
                    pa[j][0] = *(const float4*)&A[(size_t)gr * K + kn + c0];
                    pa[j][1] = *(const float4*)&A[(size_t)gr * K + kn + c0 + 4];
                } else { pa[j][0] = zf4; pa[j][1] = zf4; }
                int gn = n0 + r0 + j * 64;
                if (gn < Ntot) {
                    pbh[j] = *(const uint4*)&BThi[(size_t)gn * K + kn + c0];
                    pbl[j] = *(const uint4*)&BTlo[(size_t)gn * K + kn + c0];
                } else { pbh[j] = zero4; pbl[j] = zero4; }
            }
        }

        short8 ah[4], al[4];
#pragma unroll
        for (int mi = 0; mi < 4; mi++) {
            int row = wr * 64 + mi * 16 + fm;
            ah[mi] = *(const short8*)&sAh[row * LDA + q * 8];
            al[mi] = *(const short8*)&sAl[row * LDA + q * 8];
        }
#pragma unroll
        for (int ni = 0; ni < 4; ni++) {
            int nn = wc * 64 + ni * 16 + fm;
            short8 bh = *(const short8*)&sBh[nn * LDA + q * 8];
            short8 bl = *(const short8*)&sBl[nn * LDA + q * 8];
#pragma unroll
            for (int mi = 0; mi < 4; mi++) {
                acc[mi][ni] = __builtin_amdgcn_mfma_f32_16x16x32_bf16(ah[mi], bh, acc[mi][ni], 0, 0, 0);
                acc[mi][ni] = __builtin_amdgcn_mfma_f32_16x16x32_bf16(ah[mi], bl, acc[mi][ni], 0, 0, 0);
                acc[mi][ni] = __builtin_amdgcn_mfma_f32_16x16x32_bf16(al[mi], bh, acc[mi][ni], 0, 0, 0);
            }
        }
        __syncthreads();
    }

#pragma unroll
    for (int mi = 0; mi < 4; mi++) {
#pragma unroll
        for (int ni = 0; ni < 4; ni++) {
            int colg = n0 + wc * 64 + ni * 16 + fm;
            if (colg >= Ntot) continue;
#pragma unroll
            for (int r = 0; r < 4; r++) {
                int rowg = m0 + wr * 64 + mi * 16 + q * 4 + r;
                if (rowg >= M) continue;
                float v = acc[mi][ni][r];
                if (colg < Nb) {
                    Cb[(size_t)rowg * strideB + colg] = f2bf(v);
                } else {
                    int cf = colg - Nb;
                    Cf[(size_t)rowg * strideF + cf] = v + biasf[cf];
                }
            }
        }
    }
}

// ---------------- per-node attention coefficients (bf16 xh) ----------------
__global__ __launch_bounds__(256) void alpha_kernel(const u16* __restrict__ xh,
                                                    const float* __restrict__ a_s,
                                                    const float* __restrict__ a_d,
                                                    float* __restrict__ as_o,
                                                    float* __restrict__ ad_o, int C) {
    int n = blockIdx.x;
    int w = threadIdx.x >> 6, lane = threadIdx.x & 63;
    const u16* row = xh + (size_t)n * 4 * C + (size_t)w * C;
    float ss = 0.f, sd = 0.f;
    for (int c = lane; c < C; c += 64) {
        float v = bf2f(row[c]);
        ss += v * a_s[w * C + c];
        sd += v * a_d[w * C + c];
    }
    for (int o = 32; o; o >>= 1) {
        ss += __shfl_xor(ss, o, 64);
        sd += __shfl_xor(sd, o, 64);
    }
    if (!lane) {
        as_o[n * 4 + w] = ss;
        ad_o[n * 4 + w] = sd;
    }
}

// ---------------- fused softmax stats + per-edge alpha ----------------
__global__ __launch_bounds__(256) void stats_alpha_kernel(const int* __restrict__ rowp,
                                                          const int* __restrict__ col,
                                                          const float* __restrict__ asrc,
                                                          const float* __restrict__ adst,
                                                          float* __restrict__ alphaE, int N) {
    int i = blockIdx.x * 256 + threadIdx.x;
    if (i >= N * 4) return;
    int n = i >> 2, h = i & 3;
    int r0 = rowp[n], r1 = rowp[n + 1];
    float ad = adst[i];
    float m = -3.4e38f, s = 0.f;
    for (int e = r0; e < r1; e++) {
        int sc = col[e];
        float l = lrelu(asrc[sc * 4 + h] + ad);
        float nm = fmaxf(m, l);
        s = s * __expf(m - nm) + __expf(l - nm);
        m = nm;
    }
    float rd = 1.f / (s + 1e-16f);
    for (int e = r0; e < r1; e++) {
        int sc = col[e];
        float l = lrelu(asrc[sc * 4 + h] + ad);
        alphaE[(size_t)e * 4 + h] = __expf(l - m) * rd;
    }
}

// ---------------- gather+FMA aggregate, HC=256 (layers 1/2) ----------------
// 4 edge-groups x 64 threads x 4 channels (uint2 gathers). res/out may alias.
__global__ __launch_bounds__(256) void agg_kernel_256(const u16* __restrict__ xh,
                                                      const int* __restrict__ rowp,
                                                      const int* __restrict__ col,
                                                      const float* __restrict__ alphaE,
                                                      const float* __restrict__ bias,
                                                      const float* res,
                                                      float* out) {
    int n = blockIdx.x, tid = threadIdx.x;
    int r0 = rowp[n], deg = rowp[n + 1] - r0;
    __shared__ int s_src[64];
    __shared__ float s_al[64][4];
    __shared__ float s_part[4][HC12];
    int g = tid >> 6;          // edge group 0..3
    int sub = tid & 63;
    int c = sub * 4;           // channel quad
    int h = sub >> 4;          // c/64
    float a0 = 0.f, a1 = 0.f, a2 = 0.f, a3 = 0.f;
    for (int kb = 0; kb < deg; kb += 64) {
        int cn = min(64, deg - kb);
        __syncthreads();
        if (tid < cn) s_src[tid] = col[r0 + kb + tid];
        for (int idx = tid; idx < cn * 4; idx += 256)
            s_al[idx >> 2][idx & 3] = alphaE[(size_t)(r0 + kb) * 4 + idx];
        __syncthreads();
#pragma unroll 4
        for (int kk = g; kk < cn; kk += 4) {
            uint2 v = *(const uint2*)&xh[(size_t)s_src[kk] * HC12 + c];
            float al = s_al[kk][h];
            a0 += al * bf2f((u16)(v.x & 0xffff));
            a1 += al * bf2f((u16)(v.x >> 16));
            a2 += al * bf2f((u16)(v.y & 0xffff));
            a3 += al * bf2f((u16)(v.y >> 16));
        }
    }
    s_part[g][c] = a0; s_part[g][c + 1] = a1; s_part[g][c + 2] = a2; s_part[g][c + 3] = a3;
    __syncthreads();
    float v = s_part[0][tid] + s_part[1][tid] + s_part[2][tid] + s_part[3][tid]
              + bias[tid] + res[(size_t)n * HC12 + tid];
    out[(size_t)n * HC12 + tid] = v > 0.f ? v : expm1f(v);
}

// ---------------- layer 3 gather: HC=484, mean heads + b3 + lin3 -> d_out ----------------
__global__ __launch_bounds__(256) void agg_out_kernel(const u16* __restrict__ xh,
                                                      const int* __restrict__ rowp,
                                                      const int* __restrict__ col,
                                                      const float* __restrict__ alphaE,
                                                      const float* __restrict__ b3,
                                                      const float* __restrict__ lin3,
                                                      float* __restrict__ out) {
    int n = blockIdx.x, tid = threadIdx.x;
    int r0 = rowp[n], deg = rowp[n + 1] - r0;
    __shared__ int s_src[64];
    __shared__ float s_al[64][4];
    __shared__ float s_out[HC3];
    bool act = tid < 242;
    int c0 = 2 * tid, c1 = c0 + 1;
    int h0 = c0 >= 363 ? 3 : (c0 >= 242 ? 2 : (c0 >= 121 ? 1 : 0));
    int h1 = c1 >= 363 ? 3 : (c1 >= 242 ? 2 : (c1 >= 121 ? 1 : 0));
    float a0 = 0.f, a1 = 0.f;
    for (int kb = 0; kb < deg; kb += 64) {
        int cn = min(64, deg - kb);
        __syncthreads();
        if (tid < cn) s_src[tid] = col[r0 + kb + tid];
        for (int idx = tid; idx < cn * 4; idx += 256)
            s_al[idx >> 2][idx & 3] = alphaE[(size_t)(r0 + kb) * 4 + idx];
        __syncthreads();
        if (act) {
#pragma unroll 4
            for (int kk = 0; kk < cn; kk++) {
                u32 v = *(const u32*)&xh[(size_t)s_src[kk] * HC3 + c0];
                a0 += s_al[kk][h0] * bf2f((u16)(v & 0xffff));
                a1 += s_al[kk][h1] * bf2f((u16)(v >> 16));
            }
        }
    }
    if (act) { s_out[c0] = a0; s_out[c1] = a1; }
    __syncthreads();
    if (tid < NCLS) {
        float o = 0.25f * (s_out[tid] + s_out[NCLS + tid] + s_out[2 * NCLS + tid] + s_out[3 * NCLS + tid])
                  + b3[tid] + lin3[(size_t)n * NCLS + tid];
        out[(size_t)n * NCLS + tid] = o;
    }
}

extern "C" void kernel_launch(void* const* d_in, const int* in_sizes, int n_in,
                              void* d_out, int out_size, void* d_ws, size_t ws_size,
                              hipStream_t stream) {
    const float* x   = (const float*)d_in[0];
    const int*   ei  = (const int*)d_in[1];
    const float* W1  = (const float*)d_in[2];
    const float* a1s = (const float*)d_in[3];
    const float* a1d = (const float*)d_in[4];
    const float* b1  = (const float*)d_in[5];
    const float* l1W = (const float*)d_in[6];
    const float* l1b = (const float*)d_in[7];
    const float* W2  = (const float*)d_in[8];
    const float* a2s = (const float*)d_in[9];
    const float* a2d = (const float*)d_in[10];
    const float* b2  = (const float*)d_in[11];
    const float* W3  = (const float*)d_in[12];
    const float* a3s = (const float*)d_in[13];
    const float* a3d = (const float*)d_in[14];
    const float* b3  = (const float*)d_in[15];
    const float* l3W = (const float*)d_in[16];
    const float* l3b = (const float*)d_in[17];

    const int N = in_sizes[0] / F_IN;   // 50000
    const int E = in_sizes[1] / 2;      // 400000
    const int* srcv = ei;
    const int* dstv = ei + E;

    char* ws = (char*)d_ws;
    size_t off = 0;
    auto alloc = [&](size_t bytes) -> char* {
        char* p = ws + off;
        off += (bytes + 255) & ~(size_t)255;
        return p;
    };
    u16*   xh   = (u16*)alloc((size_t)N * HC3 * 2);
    float* h1   = (float*)alloc((size_t)N * HC12 * 4);
    float* h2   = (float*)alloc((size_t)N * HC12 * 4);
    float* lin  = (float*)alloc((size_t)N * NCLS * 4);
    float* as_  = (float*)alloc((size_t)N * 4 * 4);
    float* ad_  = (float*)alloc((size_t)N * 4 * 4);
    int* rowp   = (int*)alloc((size_t)(N + 1) * 4);
    int* degc   = (int*)alloc((size_t)N * 4);
    int* cur    = (int*)alloc((size_t)N * 4);
    int* col    = (int*)alloc((size_t)E * 4);
    float* alphaE = (float*)alloc((size_t)E * 4 * 4);
    u16* C1h = (u16*)alloc((size_t)512 * 128 * 2);
    u16* C1l = (u16*)alloc((size_t)512 * 128 * 2);
    u16* C2h = (u16*)alloc((size_t)256 * 256 * 2);
    u16* C2l = (u16*)alloc((size_t)256 * 256 * 2);
    u16* C3h = (u16*)alloc((size_t)605 * 256 * 2);
    u16* C3l = (u16*)alloc((size_t)605 * 256 * 2);
    (void)ws_size; (void)n_in; (void)out_size;

    // ---- CSR build ----
    hipMemsetAsync(degc, 0, (size_t)N * 4, stream);
    hipMemsetAsync(cur, 0, (size_t)N * 4, stream);
    hist_kernel<<<(E + 255) / 256, 256, 0, stream>>>(dstv, degc, E);
    scan_kernel<<<1, 1024, 0, stream>>>(degc, rowp, N);
    scatter_kernel<<<(E + 255) / 256, 256, 0, stream>>>(srcv, dstv, rowp, cur, col, E);

    // ---- fused weight splits ----
    splitT_all_kernel<<<(285952 + 255) / 256, 256, 0, stream>>>(W1, l1W, W2, W3, l3W,
                                                                C1h, C1l, C2h, C2l, C3h, C3l);

    int ny = (N + BM - 1) / BM;
    int sgrid = (N * 4 + 255) / 256;

    // ---- layer 1: one GEMM, N=512 (cols 0-255 -> xh bf16, 256-511 -> h1 fp32 + l1b) ----
    gemm_mfma_split<<<4 * ny, 256, 0, stream>>>(x, C1h, C1l, N, F_IN, 512, 4, ny,
                                                256, xh, 256, h1, l1b, 256);
    alpha_kernel<<<N, 256, 0, stream>>>(xh, a1s, a1d, as_, ad_, 64);
    stats_alpha_kernel<<<sgrid, 256, 0, stream>>>(rowp, col, as_, ad_, alphaE, N);
    agg_kernel_256<<<N, 256, 0, stream>>>(xh, rowp, col, alphaE, b1, h1, h1);

    // ---- layer 2: N=256, all bf16 ----
    gemm_mfma_split<<<2 * ny, 256, 0, stream>>>(h1, C2h, C2l, N, HC12, 256, 2, ny,
                                                256, xh, 256, nullptr, nullptr, 0);
    alpha_kernel<<<N, 256, 0, stream>>>(xh, a2s, a2d, as_, ad_, 64);
    stats_alpha_kernel<<<sgrid, 256, 0, stream>>>(rowp, col, as_, ad_, alphaE, N);
    agg_kernel_256<<<N, 256, 0, stream>>>(xh, rowp, col, alphaE, b2, h1, h2);

    // ---- layer 3: one GEMM, N=605 (cols 0-483 -> xh bf16, 484-604 -> lin fp32 + l3b) ----
    gemm_mfma_split<<<5 * ny, 256, 0, stream>>>(h2, C3h, C3l, N, HC12, 605, 5, ny,
                                                484, xh, 484, lin, l3b, NCLS);
    alpha_kernel<<<N, 256, 0, stream>>>(xh, a3s, a3d, as_, ad_, NCLS);
    stats_alpha_kernel<<<sgrid, 256, 0, stream>>>(rowp, col, as_, ad_, alphaE, N);
    agg_out_kernel<<<N, 256, 0, stream>>>(xh, rowp, col, alphaE, b3, lin, (float*)d_out);
}